// Round 9
// baseline (956.917 us; speedup 1.0000x reference)
//
#include <hip/hip_runtime.h>
#include <hip/hip_bf16.h>

// FeaStConv x4 on MI355X.
//  (1) (xj-xi)@u = p[src]-p[dst] with p = x@u per node (p padded to [N,8]).
//  (2) out_i = sum_h (sum_j q_h x_j) @ W_h  -> gather x_j into per-head
//      aggregates Agg[N, H*Cin], then ONE dense GEMM per layer (MFMA bf16).
// Round 9: aggregation IS an outer product -> MFMA. Per 32-edge chunk:
// T[h][c] += Q^T[6x32] X[32x128] = 8x mfma_f32_16x16x32_bf16 (A=Q via 1KB
// LDS transpose, B=X gathered directly in B-frag layout: u16 loads of
// channel l&15+16t from edges (l>>4)*8+i, row offsets via ds_bpermute).
// Replaces ~384 VALU instr/chunk (6 pk_fma + 6 readlane per edge) with
// 8 MFMA + ~120 support. Also: single-block scan -> 3-kernel parallel scan.

#define HH 6
constexpr int NN = 50000;
constexpr int NE = 1600000;
constexpr int NBK = 196;           // buckets: dst>>8, covers 50176 nodes
constexpr int SWG = 256;           // sort workgroups
constexpr int EPW = NE / SWG;      // 6250 edges per sort wg

typedef __attribute__((ext_vector_type(8))) short bf16x8;
typedef __attribute__((ext_vector_type(4))) float f32x4;
typedef __attribute__((ext_vector_type(4))) unsigned int u32x4;

static __device__ __forceinline__ float b2f(__hip_bfloat16 v) { return __bfloat162float(v); }
static __device__ __forceinline__ float u2f(unsigned short u) {
    return __uint_as_float(((unsigned int)u) << 16);
}
static __device__ __forceinline__ unsigned short f2bu(float v) {
    __hip_bfloat16 b = __float2bfloat16(v);
    return *reinterpret_cast<unsigned short*>(&b);
}
static __device__ __forceinline__ float lo2f(unsigned int w) {
    return __uint_as_float(w << 16);
}
static __device__ __forceinline__ float hi2f(unsigned int w) {
    return __uint_as_float(w & 0xffff0000u);
}
static __device__ __forceinline__ unsigned int pk2(float lo, float hi) {
    return ((unsigned int)f2bu(hi) << 16) | (unsigned int)f2bu(lo);
}
static __device__ __forceinline__ float ldf(const void* p, int i, int f32) {
    return f32 ? ((const float*)p)[i] : b2f(((const __hip_bfloat16*)p)[i]);
}
static __device__ __forceinline__ int ldi(const int* e32, int i, int i64) {
    return i64 ? e32[2 * i] : e32[i];
}
// async global->LDS: each lane copies 4B; lane i lands at ldst + i*4
static __device__ __forceinline__ void dma4(const void* g, void* l) {
    __builtin_amdgcn_global_load_lds(
        (const __attribute__((address_space(1))) void*)g,
        (__attribute__((address_space(3))) void*)l, 4, 0, 0);
}

// ---------------- dtype detection ----------------
__global__ void k_detect(const void* pos, const void* ei, int* flags) {
    __shared__ float smax[256];
    __shared__ int anynz;
    int t = threadIdx.x;
    if (t == 0) anynz = 0;
    const __hip_bfloat16* pb = (const __hip_bfloat16*)pos;
    float m = 0.f;
    for (int i = t; i < 2048; i += 256) {
        float v = fabsf(b2f(pb[i]));
        if (v != v) v = 1e30f;
        m = fmaxf(m, v);
    }
    smax[t] = m;
    __syncthreads();
    for (int s = 128; s > 0; s >>= 1) {
        if (t < s) smax[t] = fmaxf(smax[t], smax[t + s]);
        __syncthreads();
    }
    const int* e32 = (const int*)ei;
    if (t < 128 && e32[2 * t + 1] != 0) anynz = 1;
    __syncthreads();
    if (t == 0) {
        flags[0] = (smax[0] > 1e6f) ? 1 : 0;
        flags[1] = anynz ? 0 : 1;
    }
}

// ---------------- input assembly: x0 bf16 [N,8] (pads 0) ----------------
__global__ void k_build_x0(const void* __restrict__ pos, const void* __restrict__ nrm,
                           unsigned short* __restrict__ x0b, const int* __restrict__ flags) {
    int f32 = flags[0];
    int i = blockIdx.x * blockDim.x + threadIdx.x;
    if (i >= NN) return;
#pragma unroll
    for (int j = 0; j < 3; j++) {
        x0b[i * 8 + j]     = f32 ? f2bu(((const float*)pos)[i * 3 + j])
                                 : ((const unsigned short*)pos)[i * 3 + j];
        x0b[i * 8 + 3 + j] = f32 ? f2bu(((const float*)nrm)[i * 3 + j])
                                 : ((const unsigned short*)nrm)[i * 3 + j];
    }
    x0b[i * 8 + 6] = 0;
    x0b[i * 8 + 7] = 0;
}

// ---------------- CSR build: two-level counting sort ----------------
__global__ void __launch_bounds__(256) k_sortA(const int* __restrict__ ei,
                                               int* __restrict__ counts,
                                               int* __restrict__ cntT,
                                               const int* __restrict__ flags) {
    __shared__ int hist[NBK];
    int i64 = flags[1];
    int t = threadIdx.x, w = blockIdx.x;
    for (int b = t; b < NBK; b += 256) hist[b] = 0;
    __syncthreads();
    int start = w * EPW, end = start + EPW;
    for (int e = start + t; e < end; e += 256) {
        int d = ldi(ei, NE + e, i64);
        atomicAdd(&counts[d], 1);
        atomicAdd(&hist[d >> 8], 1);
    }
    __syncthreads();
    for (int b = t; b < NBK; b += 256) cntT[b * SWG + w] = hist[b];
}

// -------- parallel 3-phase exclusive scan over two arrays --------
// phase 1: per-block local exclusive scan + block sums
__global__ void __launch_bounds__(256) k_scan_local(const int* __restrict__ a0, int n0,
                                                    const int* __restrict__ a1, int n1,
                                                    int* __restrict__ o0, int* __restrict__ o1,
                                                    int* __restrict__ bsums, int nb0) {
    __shared__ int ws[4];
    int b = blockIdx.x;
    const int* a;
    int* o;
    int n, cbase;
    if (b < nb0) { a = a0; o = o0; n = n0; cbase = b * 256; }
    else { a = a1; o = o1; n = n1; cbase = (b - nb0) * 256; }
    int t = threadIdx.x, lane = t & 63, wid = t >> 6;
    int idx = cbase + t;
    int v = (idx < n) ? a[idx] : 0;
    int incl = v;
#pragma unroll
    for (int off = 1; off < 64; off <<= 1) {
        int nb = __shfl_up(incl, off, 64);
        if (lane >= off) incl += nb;
    }
    if (lane == 63) ws[wid] = incl;
    __syncthreads();
    int wpre = 0, tot = 0;
#pragma unroll
    for (int wi = 0; wi < 4; wi++) {
        int s = ws[wi];
        if (wi < wid) wpre += s;
        tot += s;
    }
    if (idx < n) o[idx] = wpre + incl - v;
    if (t == 0) bsums[b] = tot;
}

// phase 2: scan the block sums (2 blocks: one per segment of 196)
__global__ void __launch_bounds__(256) k_scan_sums(const int* __restrict__ bsums,
                                                   int* __restrict__ bpre,
                                                   int* __restrict__ o0, int n0,
                                                   int* __restrict__ o1, int n1) {
    __shared__ int ws[4];
    int blk = blockIdx.x;
    int t = threadIdx.x, lane = t & 63, wid = t >> 6;
    int base = blk * 196;
    int v = (t < 196) ? bsums[base + t] : 0;
    int incl = v;
#pragma unroll
    for (int off = 1; off < 64; off <<= 1) {
        int nb = __shfl_up(incl, off, 64);
        if (lane >= off) incl += nb;
    }
    if (lane == 63) ws[wid] = incl;
    __syncthreads();
    int wpre = 0, tot = 0;
#pragma unroll
    for (int wi = 0; wi < 4; wi++) {
        int s = ws[wi];
        if (wi < wid) wpre += s;
        tot += s;
    }
    if (t < 196) bpre[base + t] = wpre + incl - v;
    if (t == 0) {
        if (blk == 0) o0[n0] = tot;
        else o1[n1] = tot;
    }
}

// phase 3: add block prefixes
__global__ void __launch_bounds__(256) k_scan_add(int* __restrict__ o0, int n0,
                                                  int* __restrict__ o1, int n1,
                                                  const int* __restrict__ bpre, int nb0) {
    int b = blockIdx.x;
    int* o;
    int n, cbase;
    if (b < nb0) { o = o0; n = n0; cbase = b * 256; }
    else { o = o1; n = n1; cbase = (b - nb0) * 256; }
    int idx = cbase + threadIdx.x;
    if (idx < n) o[idx] += bpre[b];
}

__global__ void __launch_bounds__(256) k_sortB(const int* __restrict__ ei,
                                               const int* __restrict__ base2,
                                               unsigned int* __restrict__ ebuck,
                                               const int* __restrict__ flags) {
    __shared__ int cur[NBK];
    int i64 = flags[1];
    int t = threadIdx.x, w = blockIdx.x;
    for (int b = t; b < NBK; b += 256) cur[b] = base2[b * SWG + w];
    __syncthreads();
    int start = w * EPW, end = start + EPW;
    for (int e = start + t; e < end; e += 256) {
        int s = ldi(ei, e, i64), d = ldi(ei, NE + e, i64);
        int slot = atomicAdd(&cur[d >> 8], 1);
        ebuck[slot] = (unsigned int)s | ((unsigned int)(d & 255) << 16);
    }
}

__global__ void __launch_bounds__(256) k_sortC(const unsigned int* __restrict__ ebuck,
                                               const int* __restrict__ base2,
                                               const int* __restrict__ offs,
                                               int* __restrict__ ssrc) {
    __shared__ int cur[256];
    int t = threadIdx.x, b = blockIdx.x;
    int gn = b * 256 + t;
    cur[t] = (gn < NN) ? offs[gn] : NE;
    __syncthreads();
    int bs = base2[b * SWG], be = base2[(b + 1) * SWG];
    for (int e = bs + t; e < be; e += 256) {
        unsigned int rec = ebuck[e];
        int slot = atomicAdd(&cur[(rec >> 16) & 255], 1);
        ssrc[slot] = (int)(rec & 0xffffu);
    }
}

// ---------------- p = x @ u  ->  p8 [N,8] fp32 (h<6 valid) ----------------
__global__ void __launch_bounds__(256) k_compute_p6(const unsigned short* __restrict__ x0b,
                                                    const void* __restrict__ u,
                                                    float* __restrict__ p8,
                                                    const int* __restrict__ flags) {
    int f32 = flags[0];
    int wave = (blockIdx.x * blockDim.x + threadIdx.x) >> 6;
    int lane = threadIdx.x & 63;
    if (wave >= NN) return;
    float acc[HH] = {0, 0, 0, 0, 0, 0};
    if (lane < 6) {
        float xv = u2f(x0b[(size_t)wave * 8 + lane]);
#pragma unroll
        for (int h = 0; h < HH; h++) acc[h] = xv * ldf(u, lane * HH + h, f32);
    }
#pragma unroll
    for (int off = 4; off > 0; off >>= 1) {
#pragma unroll
        for (int h = 0; h < HH; h++) acc[h] += __shfl_down(acc[h], off, 64);
    }
    if (lane == 0) {
#pragma unroll
        for (int h = 0; h < HH; h++) p8[(size_t)wave * 8 + h] = acc[h];
    }
}

__global__ void __launch_bounds__(256) k_compute_p128(const unsigned short* __restrict__ x,
                                                      const void* __restrict__ u,
                                                      float* __restrict__ p8,
                                                      const int* __restrict__ flags) {
    int f32 = flags[0];
    int wave = (blockIdx.x * blockDim.x + threadIdx.x) >> 6;
    int lane = threadIdx.x & 63;
    if (wave >= NN) return;
    unsigned int w = *(const unsigned int*)(x + (size_t)wave * 128 + 2 * lane);
    float x0 = lo2f(w);
    float x1 = hi2f(w);
    float acc[HH];
#pragma unroll
    for (int h = 0; h < HH; h++)
        acc[h] = x0 * ldf(u, (2 * lane) * HH + h, f32) + x1 * ldf(u, (2 * lane + 1) * HH + h, f32);
#pragma unroll
    for (int off = 32; off > 0; off >>= 1) {
#pragma unroll
        for (int h = 0; h < HH; h++) acc[h] += __shfl_down(acc[h], off, 64);
    }
    if (lane == 0) {
#pragma unroll
        for (int h = 0; h < HH; h++) p8[(size_t)wave * 8 + h] = acc[h];
    }
}

// ---------------- fused softmax + aggregation, CIN=128 (MFMA) -------------
// 256 threads = 4 waves, wave per node. Chunk = 32 edges:
//   T[h][c] += Q^T[6x32] @ X[32x128]  via 8x mfma_f32_16x16x32_bf16.
// A-frag = Q (m=head, k=edge) through a 1KB/wave LDS transpose.
// B-frag = X gathered directly in fragment layout: lane l loads channel
// (16t + l&15) of edges (l>>4)*8+i as u16; row offsets via ds_bpermute.
// D[row=lq*4+r (=head), col=l15 (=channel within tile)].
__global__ void __launch_bounds__(256) k_agg128(const unsigned short* __restrict__ xb,
                                                const float* __restrict__ p8,
                                                const void* __restrict__ cvec,
                                                const int* __restrict__ ssrc,
                                                const int* __restrict__ offs,
                                                unsigned short* __restrict__ agg,
                                                const int* __restrict__ flags) {
    __shared__ unsigned short qlds[4][16 * 32];   // [wave][head(16 pad)][edge 32]
    int f32 = flags[0];
    int wid = threadIdx.x >> 6, lane = threadIdx.x & 63;
    int l15 = lane & 15, lq = lane >> 4;
    int node = (blockIdx.x * blockDim.x + threadIdx.x) >> 6;
    if (node >= NN) return;
    int s0 = offs[node], s1 = offs[node + 1];
    int deg = s1 - s0;
    float scale = 1.0f / (float)(deg > 0 ? deg : 1);
    const float* pn = p8 + (size_t)node * 8;
    float pd[HH];
#pragma unroll
    for (int h = 0; h < HH; h++) pd[h] = pn[h] - ldf(cvec, h, f32);

    unsigned short* ql = &qlds[wid][0];
    const char* xc = (const char*)xb;
    f32x4 acc[8] = {};                       // 8 channel tiles x 4 head-regs

    for (int base = s0; base < s1; base += 32) {
        // ---- phase A: lanes 0..31 = edges; q (bf16) -> LDS [h][e] ----
        unsigned int rowByte = 0;
        if (lane < 32) {
            int e = base + lane;
            float q0 = 0, q1 = 0, q2 = 0, q3 = 0, q4 = 0, q5 = 0;
            if (e < s1) {
                int j = ssrc[e];
                const float* pj = p8 + (size_t)j * 8;
                float4 pa = *(const float4*)pj;
                float2 pb = *(const float2*)(pj + 4);
                float t0 = pa.x - pd[0], t1 = pa.y - pd[1], t2 = pa.z - pd[2];
                float t3 = pa.w - pd[3], t4 = pb.x - pd[4], t5 = pb.y - pd[5];
                float mx = fmaxf(fmaxf(fmaxf(t0, t1), fmaxf(t2, t3)), fmaxf(t4, t5));
                q0 = __expf(t0 - mx); q1 = __expf(t1 - mx); q2 = __expf(t2 - mx);
                q3 = __expf(t3 - mx); q4 = __expf(t4 - mx); q5 = __expf(t5 - mx);
                float inv = 1.0f / (q0 + q1 + q2 + q3 + q4 + q5);
                q0 *= inv; q1 *= inv; q2 *= inv; q3 *= inv; q4 *= inv; q5 *= inv;
                rowByte = (unsigned int)j * 256u;      // row = 128 bf16 = 256 B
            }
            ql[0 * 32 + lane] = f2bu(q0);
            ql[1 * 32 + lane] = f2bu(q1);
            ql[2 * 32 + lane] = f2bu(q2);
            ql[3 * 32 + lane] = f2bu(q3);
            ql[4 * 32 + lane] = f2bu(q4);
            ql[5 * 32 + lane] = f2bu(q5);
        }
        // ---- A-frag: Q[head=l15][edge=lq*8..+8] (rows 6..15 garbage, unused)
        bf16x8 afrag = *(const bf16x8*)(ql + l15 * 32 + lq * 8);
        // ---- broadcast row offsets of this lane's 8 edges ----
        unsigned int voff[8];
#pragma unroll
        for (int i = 0; i < 8; i++) {
            int sel = ((lane >> 4) * 8 + i) * 4;
            unsigned int vr = (unsigned int)__builtin_amdgcn_ds_bpermute(sel, (int)rowByte);
            voff[i] = vr + 2u * (unsigned int)l15;
        }
        // ---- 8 channel tiles: gather B-frag + MFMA ----
#pragma unroll
        for (int t = 0; t < 8; t++) {
            unsigned short xv[8];
#pragma unroll
            for (int i = 0; i < 8; i++)
                xv[i] = *(const unsigned short*)(xc + (size_t)voff[i] + t * 32);
            u32x4 pkd;
#pragma unroll
            for (int i = 0; i < 4; i++)
                pkd[i] = (unsigned int)xv[2 * i] | ((unsigned int)xv[2 * i + 1] << 16);
            bf16x8 bfrag = __builtin_bit_cast(bf16x8, pkd);
            acc[t] = __builtin_amdgcn_mfma_f32_16x16x32_bf16(afrag, bfrag, acc[t], 0, 0, 0);
        }
    }
    // ---- epilogue: D[head=lq*4+r][ch=16t+l15] ----
    unsigned short* ar = agg + (size_t)node * 768;
#pragma unroll
    for (int t = 0; t < 8; t++) {
#pragma unroll
        for (int r = 0; r < 4; r++) {
            int h = lq * 4 + r;
            if (h < HH) ar[h * 128 + t * 16 + l15] = f2bu(acc[t][r] * scale);
        }
    }
}

// ---------------- fused softmax + aggregation, CIN=6 (DMA staged) ---------
__global__ void __launch_bounds__(256) k_agg6(const unsigned short* __restrict__ xb,
                                              const float* __restrict__ p8,
                                              const void* __restrict__ cvec,
                                              const int* __restrict__ ssrc,
                                              const int* __restrict__ offs,
                                              float* __restrict__ agg,
                                              const int* __restrict__ flags) {
    __shared__ unsigned short stage6[4][64 * 8];     // 4 KB: 64 rows x 16 B
    __shared__ float qsf[4][64][8];                  // 8 KB: q[6] + rowbyte bits
    int f32 = flags[0];
    int wid = threadIdx.x >> 6, lane = threadIdx.x & 63;
    int node = (blockIdx.x * blockDim.x + threadIdx.x) >> 6;
    if (node >= NN) return;
    int s0 = offs[node], s1 = offs[node + 1];
    int deg = s1 - s0;
    float scale = 1.0f / (float)(deg > 0 ? deg : 1);
    const float* pn = p8 + (size_t)node * 8;
    float pd[HH];
#pragma unroll
    for (int h = 0; h < HH; h++) pd[h] = pn[h] - ldf(cvec, h, f32);

    float acc6 = 0.f;
    int hh6 = lane / 6, kk6 = lane - hh6 * 6;
    const char* xbase = (const char*)xb;
    for (int base = s0; base < s1; base += 64) {
        int cnt = (s1 - base < 64) ? (s1 - base) : 64;
        {
            int e = base + lane;
            float q0 = 0, q1 = 0, q2 = 0, q3 = 0, q4 = 0, q5 = 0;
            unsigned int rowByte = 0;
            if (e < s1) {
                int j = ssrc[e];
                const float* pj = p8 + (size_t)j * 8;
                float4 pa = *(const float4*)pj;
                float2 pb = *(const float2*)(pj + 4);
                float t0 = pa.x - pd[0], t1 = pa.y - pd[1], t2 = pa.z - pd[2];
                float t3 = pa.w - pd[3], t4 = pb.x - pd[4], t5 = pb.y - pd[5];
                float mx = fmaxf(fmaxf(fmaxf(t0, t1), fmaxf(t2, t3)), fmaxf(t4, t5));
                q0 = __expf(t0 - mx); q1 = __expf(t1 - mx); q2 = __expf(t2 - mx);
                q3 = __expf(t3 - mx); q4 = __expf(t4 - mx); q5 = __expf(t5 - mx);
                float inv = 1.0f / (q0 + q1 + q2 + q3 + q4 + q5);
                q0 *= inv; q1 *= inv; q2 *= inv; q3 *= inv; q4 *= inv; q5 *= inv;
                rowByte = (unsigned int)j * 16u;
            }
            float4 qa = {q0, q1, q2, q3};
            float4 qb = {q4, q5, __uint_as_float(rowByte), 0.f};
            *(float4*)&qsf[wid][lane][0] = qa;
            *(float4*)&qsf[wid][lane][4] = qb;
        }
        __builtin_amdgcn_sched_barrier(0);
#pragma unroll
        for (int t = 0; t < 4; t++) {
            int r = t * 16 + (lane >> 2);
            unsigned int rb = __float_as_uint(qsf[wid][r][6]);
            dma4(xbase + rb + (lane & 3) * 4, &stage6[wid][t * 128]);
        }
        __builtin_amdgcn_s_waitcnt(0x0f70);          // vmcnt(0) only
        __builtin_amdgcn_sched_barrier(0);
        if (lane < 36) {
            for (int s = 0; s < cnt; s++) {
                float qh = qsf[wid][s][hh6];
                float xv = u2f(stage6[wid][s * 8 + kk6]);
                acc6 = fmaf(qh, xv, acc6);
            }
        }
        __builtin_amdgcn_sched_barrier(0);
    }
    if (lane < 36) agg[(size_t)node * 36 + lane] = acc6 * scale;
}

// ---------------- fused weight repacks ----------------
__global__ void k_repack_all(const void* __restrict__ W1, const void* __restrict__ W2,
                             const void* __restrict__ W3, const void* __restrict__ W4,
                             float* __restrict__ wstk1, unsigned short* __restrict__ wt2,
                             unsigned short* __restrict__ wt3, float* __restrict__ wstk4,
                             const int* __restrict__ flags) {
    int f32 = flags[0];
    int idx = blockIdx.x * blockDim.x + threadIdx.x;
    if (idx < 4608) {
        int f = idx & 127, m = idx >> 7;
        int h = m / 6, k = m - h * 6;
        wstk1[idx] = ldf(W1, k * 768 + h * 128 + f, f32);
        return;
    }
    idx -= 4608;
    if (idx < 98304) {
        int f = idx / 768, m = idx % 768;
        int h = m >> 7, kk = m & 127;
        wt2[idx] = f2bu(ldf(W2, kk * 768 + h * 128 + f, f32));
        return;
    }
    idx -= 98304;
    if (idx < 98304) {
        int f = idx / 768, m = idx % 768;
        int h = m >> 7, kk = m & 127;
        wt3[idx] = f2bu(ldf(W3, kk * 768 + h * 128 + f, f32));
        return;
    }
    idx -= 98304;
    if (idx < 2304) {
        int f = idx % 3, m = idx / 3;
        int h = m >> 7, k = m & 127;
        wstk4[idx] = ldf(W4, k * 18 + h * 3 + f, f32);
    }
}

// ---------------- layer-1 GEMM (fp32, K=36), writes bf16 x ----------------
__global__ void __launch_bounds__(256) k_gemm_f32(const float* __restrict__ A,
                                                  const float* __restrict__ B,
                                                  const void* __restrict__ bias,
                                                  unsigned short* __restrict__ C,
                                                  int M, int K, int relu,
                                                  const int* __restrict__ flags) {
    int f32 = flags[0];
    __shared__ float As[16][68];
    __shared__ float Bs[16][128];
    int tid = threadIdx.x;
    int tx = tid & 15;
    int ty = tid >> 4;
    int bm = blockIdx.x * 64;
    int arow = tid >> 2, ak = (tid & 3) * 4;
    int brow = tid >> 4, bcol = (tid & 15) * 8;
    float acc[4][8] = {};
    for (int k0 = 0; k0 < K; k0 += 16) {
        float4 av = {0, 0, 0, 0};
        int gr = bm + arow;
        if (gr < M && (k0 + ak) < K) av = *(const float4*)(A + (size_t)gr * K + k0 + ak);
        As[ak + 0][arow] = av.x;
        As[ak + 1][arow] = av.y;
        As[ak + 2][arow] = av.z;
        As[ak + 3][arow] = av.w;
        float4 bv0 = {0, 0, 0, 0}, bv1 = {0, 0, 0, 0};
        if ((k0 + brow) < K) {
            const float* bp = B + (size_t)(k0 + brow) * 128 + bcol;
            bv0 = *(const float4*)bp;
            bv1 = *(const float4*)(bp + 4);
        }
        *(float4*)&Bs[brow][bcol]     = bv0;
        *(float4*)&Bs[brow][bcol + 4] = bv1;
        __syncthreads();
#pragma unroll
        for (int kk = 0; kk < 16; kk++) {
            float a_[4], b_[8];
#pragma unroll
            for (int j = 0; j < 4; j++) a_[j] = As[kk][ty * 4 + j];
#pragma unroll
            for (int j = 0; j < 8; j++) b_[j] = Bs[kk][tx * 8 + j];
#pragma unroll
            for (int i = 0; i < 4; i++)
#pragma unroll
                for (int j = 0; j < 8; j++) acc[i][j] = fmaf(a_[i], b_[j], acc[i][j]);
        }
        __syncthreads();
    }
#pragma unroll
    for (int i = 0; i < 4; i++) {
        int row = bm + ty * 4 + i;
        if (row >= M) continue;
#pragma unroll
        for (int j = 0; j < 8; j++) {
            int col = tx * 8 + j;
            float v = acc[i][j] + ldf(bias, col, f32);
            if (relu) v = fmaxf(v, 0.f);
            C[(size_t)row * 128 + col] = f2bu(v);
        }
    }
}

// ---------------- MFMA GEMM: C[M,128] = A[M,768]bf16 @ Wt^T + bias, ReLU ----
__global__ void __launch_bounds__(256) k_gemm_mfma(const unsigned short* __restrict__ A,
                                                   const unsigned short* __restrict__ Bt,
                                                   const void* __restrict__ bias,
                                                   unsigned short* __restrict__ C,
                                                   int M, int relu,
                                                   const int* __restrict__ flags) {
    constexpr int K = 768, BK = 64;
    __shared__ unsigned short As[64][72];
    __shared__ unsigned short Bs[128][72];
    int f32 = flags[0];
    int tid = threadIdx.x;
    int lane = tid & 63, wid = tid >> 6;
    int wm = wid & 1, wn = wid >> 1;
    int bm = blockIdx.x * 64;
    int l15 = lane & 15, lq = lane >> 4;
    f32x4 acc[2][4] = {};

    for (int k0 = 0; k0 < K; k0 += BK) {
#pragma unroll
        for (int cc = 0; cc < 2; cc++) {
            int c = tid + cc * 256;
            int r = c >> 3, kc = (c & 7) * 8;
            bf16x8 av = {};
            int gr = bm + r;
            if (gr < M) av = *(const bf16x8*)(A + (size_t)gr * K + k0 + kc);
            *(bf16x8*)&As[r][kc] = av;
        }
#pragma unroll
        for (int cc = 0; cc < 4; cc++) {
            int c = tid + cc * 256;
            int n = c >> 3, kc = (c & 7) * 8;
            *(bf16x8*)&Bs[n][kc] = *(const bf16x8*)(Bt + (size_t)n * K + k0 + kc);
        }
        __syncthreads();
#pragma unroll
        for (int ks = 0; ks < BK; ks += 32) {
            int koff = ks + lq * 8;
            bf16x8 af[2], bfr[4];
#pragma unroll
            for (int tm = 0; tm < 2; tm++)
                af[tm] = *(const bf16x8*)&As[wm * 32 + tm * 16 + l15][koff];
#pragma unroll
            for (int tn = 0; tn < 4; tn++)
                bfr[tn] = *(const bf16x8*)&Bs[wn * 64 + tn * 16 + l15][koff];
#pragma unroll
            for (int tm = 0; tm < 2; tm++)
#pragma unroll
                for (int tn = 0; tn < 4; tn++)
                    acc[tm][tn] = __builtin_amdgcn_mfma_f32_16x16x32_bf16(
                        af[tm], bfr[tn], acc[tm][tn], 0, 0, 0);
        }
        __syncthreads();
    }
#pragma unroll
    for (int tm = 0; tm < 2; tm++) {
#pragma unroll
        for (int tn = 0; tn < 4; tn++) {
            int col = wn * 64 + tn * 16 + l15;
            float bv = ldf(bias, col, f32);
#pragma unroll
            for (int r = 0; r < 4; r++) {
                int row = bm + wm * 32 + tm * 16 + lq * 4 + r;
                if (row < M) {
                    float v = acc[tm][tn][r] + bv;
                    if (relu) v = fmaxf(v, 0.f);
                    C[(size_t)row * 128 + col] = f2bu(v);
                }
            }
        }
    }
}

// ---------------- final layer ----------------
__global__ void __launch_bounds__(256) k_final(const unsigned short* __restrict__ agg,
                                               const float* __restrict__ wstk,
                                               const void* __restrict__ bias,
                                               void* __restrict__ out,
                                               const int* __restrict__ flags) {
    int f32 = flags[0];
    int node = (blockIdx.x * blockDim.x + threadIdx.x) >> 6;
    int lane = threadIdx.x & 63;
    if (node >= NN) return;
    float f0 = 0, f1 = 0, f2 = 0;
    const unsigned short* ar = agg + (size_t)node * 768;
#pragma unroll
    for (int it = 0; it < 6; it++) {
        int m = it * 128 + 2 * lane;
        unsigned int w = *(const unsigned int*)(ar + m);
        float a0 = lo2f(w);
        float a1 = hi2f(w);
        f0 += a0 * wstk[m * 3 + 0] + a1 * wstk[m * 3 + 3];
        f1 += a0 * wstk[m * 3 + 1] + a1 * wstk[m * 3 + 4];
        f2 += a0 * wstk[m * 3 + 2] + a1 * wstk[m * 3 + 5];
    }
#pragma unroll
    for (int off = 32; off > 0; off >>= 1) {
        f0 += __shfl_down(f0, off, 64);
        f1 += __shfl_down(f1, off, 64);
        f2 += __shfl_down(f2, off, 64);
    }
    if (lane == 0) {
        float r0 = f0 + ldf(bias, 0, f32);
        float r1 = f1 + ldf(bias, 1, f32);
        float r2 = f2 + ldf(bias, 2, f32);
        if (f32) {
            float* o = (float*)out;
            o[(size_t)node * 3 + 0] = r0;
            o[(size_t)node * 3 + 1] = r1;
            o[(size_t)node * 3 + 2] = r2;
        } else {
            __hip_bfloat16* o = (__hip_bfloat16*)out;
            o[(size_t)node * 3 + 0] = __float2bfloat16(r0);
            o[(size_t)node * 3 + 1] = __float2bfloat16(r1);
            o[(size_t)node * 3 + 2] = __float2bfloat16(r2);
        }
    }
}

extern "C" void kernel_launch(void* const* d_in, const int* in_sizes, int n_in,
                              void* d_out, int out_size, void* d_ws, size_t ws_size,
                              hipStream_t stream) {
    (void)in_sizes; (void)n_in; (void)out_size; (void)ws_size;
    const void* pos = d_in[0];
    const void* nrm = d_in[1];
    const int* ei = (const int*)d_in[2];
    const void* W[4] = {d_in[3], d_in[7], d_in[11], d_in[15]};
    const void* U[4] = {d_in[4], d_in[8], d_in[12], d_in[16]};
    const void* Cc[4] = {d_in[5], d_in[9], d_in[13], d_in[17]};
    const void* Bb[4] = {d_in[6], d_in[10], d_in[14], d_in[18]};

    char* wp = (char*)d_ws;
    auto alloc = [&](size_t b) { void* r = (void*)wp; wp += (b + 255) & ~(size_t)255; return r; };
    unsigned short* xA  = (unsigned short*)alloc((size_t)NN * 128 * 2);
    unsigned short* xB  = (unsigned short*)alloc((size_t)NN * 128 * 2);
    unsigned short* x0b = (unsigned short*)alloc((size_t)NN * 8 * 2);
    float* p8     = (float*)alloc((size_t)NN * 8 * 4);
    int*   counts = (int*)alloc((size_t)NN * 4);
    int*   offs   = (int*)alloc((size_t)(NN + 1) * 4);
    int*   cntT   = (int*)alloc((size_t)NBK * SWG * 4);
    int*   base2  = (int*)alloc((size_t)(NBK * SWG + 1) * 4);
    int*   bsums  = (int*)alloc((size_t)512 * 4);
    int*   bpre   = (int*)alloc((size_t)512 * 4);
    int*   flags  = (int*)alloc(256);
    int*   ssrc   = (int*)alloc((size_t)NE * 4);
    unsigned int* ebuck = (unsigned int*)alloc((size_t)NE * 4);
    void*  aggv   = alloc((size_t)NN * 768 * 2);
    float* wstk1  = (float*)alloc((size_t)36 * 128 * 4);
    unsigned short* wt2 = (unsigned short*)alloc((size_t)128 * 768 * 2);
    unsigned short* wt3 = (unsigned short*)alloc((size_t)128 * 768 * 2);
    float* wstk4  = (float*)alloc((size_t)768 * 3 * 4);
    unsigned short* agg_h = (unsigned short*)aggv;
    float* agg_f = (float*)aggv;

    const int NB = (NN + 255) / 256;
    const int NWB = (NN * 64 + 255) / 256;      // 256-thread wave-per-node grids
    const int GB = (NN + 63) / 64;

    k_detect<<<1, 256, 0, stream>>>(pos, ei, flags);
    hipMemsetAsync(counts, 0, (size_t)NN * 4, stream);
    k_sortA<<<SWG, 256, 0, stream>>>(ei, counts, cntT, flags);
    k_scan_local<<<392, 256, 0, stream>>>(counts, NN, cntT, NBK * SWG, offs, base2, bsums, 196);
    k_scan_sums<<<2, 256, 0, stream>>>(bsums, bpre, offs, NN, base2, NBK * SWG);
    k_scan_add<<<392, 256, 0, stream>>>(offs, NN, base2, NBK * SWG, bpre, 196);
    k_sortB<<<SWG, 256, 0, stream>>>(ei, base2, ebuck, flags);
    k_sortC<<<NBK, 256, 0, stream>>>(ebuck, base2, offs, ssrc);
    k_build_x0<<<NB, 256, 0, stream>>>(pos, nrm, x0b, flags);
    k_repack_all<<<(203520 + 255) / 256, 256, 0, stream>>>(W[0], W[1], W[2], W[3],
                                                           wstk1, wt2, wt3, wstk4, flags);

    // ---- layer 1: 6 -> 128, relu ----
    k_compute_p6<<<NWB, 256, 0, stream>>>(x0b, U[0], p8, flags);
    k_agg6<<<NWB, 256, 0, stream>>>(x0b, p8, Cc[0], ssrc, offs, agg_f, flags);
    k_gemm_f32<<<GB, 256, 0, stream>>>(agg_f, wstk1, Bb[0], xA, NN, 36, 1, flags);

    // ---- layer 2: 128 -> 128, relu ----
    k_compute_p128<<<NWB, 256, 0, stream>>>(xA, U[1], p8, flags);
    k_agg128<<<NWB, 256, 0, stream>>>(xA, p8, Cc[1], ssrc, offs, agg_h, flags);
    k_gemm_mfma<<<GB, 256, 0, stream>>>(agg_h, wt2, Bb[1], xB, NN, 1, flags);

    // ---- layer 3: 128 -> 128, relu ----
    k_compute_p128<<<NWB, 256, 0, stream>>>(xB, U[2], p8, flags);
    k_agg128<<<NWB, 256, 0, stream>>>(xB, p8, Cc[2], ssrc, offs, agg_h, flags);
    k_gemm_mfma<<<GB, 256, 0, stream>>>(agg_h, wt3, Bb[2], xA, NN, 1, flags);

    // ---- layer 4: 128 -> 3 ----
    k_compute_p128<<<NWB, 256, 0, stream>>>(xA, U[3], p8, flags);
    k_agg128<<<NWB, 256, 0, stream>>>(xA, p8, Cc[3], ssrc, offs, agg_h, flags);
    k_final<<<NWB, 256, 0, stream>>>(agg_h, wstk4, Bb[3], d_out, flags);
}

// Round 10
// 679.273 us; speedup vs baseline: 1.4087x; 1.4087x over previous
//
#include <hip/hip_runtime.h>
#include <hip/hip_bf16.h>

// FeaStConv x4 on MI355X.
//  (1) (xj-xi)@u = p[src]-p[dst] with p = x@u per node (p padded to [N,8]).
//  (2) layers 1-3: aggregate-then-transform (gather x 256B/edge -> Agg ->
//      dense MFMA GEMM). Layer 4: TRANSFORM-FIRST (Cout*H=18 << Cin=128):
//      y4 = x@W4 [N,18] fp32 (tiny MFMA GEMM, L2-resident), final kernel
//      gathers 80B/edge, each lane owns its edge (no broadcasts).
// Round 10: revert r9's MFMA aggregation (2x vmem instrs, regressed);
// back to r8 LDS-free agg128 + q packed as 3 bf16-pair dwords (4 readlanes
// per edge instead of 7, SALU unpack co-issues).

#define HH 6
constexpr int NN = 50000;
constexpr int NE = 1600000;
constexpr int NBK = 196;           // buckets: dst>>8, covers 50176 nodes
constexpr int SWG = 256;           // sort workgroups
constexpr int EPW = NE / SWG;      // 6250 edges per sort wg

typedef __attribute__((ext_vector_type(8))) short bf16x8;
typedef __attribute__((ext_vector_type(4))) float f32x4;
typedef __attribute__((ext_vector_type(2))) float f32x2;

static __device__ __forceinline__ float b2f(__hip_bfloat16 v) { return __bfloat162float(v); }
static __device__ __forceinline__ float u2f(unsigned short u) {
    return __uint_as_float(((unsigned int)u) << 16);
}
static __device__ __forceinline__ unsigned short f2bu(float v) {
    __hip_bfloat16 b = __float2bfloat16(v);
    return *reinterpret_cast<unsigned short*>(&b);
}
static __device__ __forceinline__ float lo2f(unsigned int w) {
    return __uint_as_float(w << 16);
}
static __device__ __forceinline__ float hi2f(unsigned int w) {
    return __uint_as_float(w & 0xffff0000u);
}
static __device__ __forceinline__ unsigned int pk2(float lo, float hi) {
    return ((unsigned int)f2bu(hi) << 16) | (unsigned int)f2bu(lo);
}
static __device__ __forceinline__ float ldf(const void* p, int i, int f32) {
    return f32 ? ((const float*)p)[i] : b2f(((const __hip_bfloat16*)p)[i]);
}
static __device__ __forceinline__ int ldi(const int* e32, int i, int i64) {
    return i64 ? e32[2 * i] : e32[i];
}
// async global->LDS: each lane copies 4B; lane i lands at ldst + i*4
static __device__ __forceinline__ void dma4(const void* g, void* l) {
    __builtin_amdgcn_global_load_lds(
        (const __attribute__((address_space(1))) void*)g,
        (__attribute__((address_space(3))) void*)l, 4, 0, 0);
}

// ---------------- dtype detection ----------------
__global__ void k_detect(const void* pos, const void* ei, int* flags) {
    __shared__ float smax[256];
    __shared__ int anynz;
    int t = threadIdx.x;
    if (t == 0) anynz = 0;
    const __hip_bfloat16* pb = (const __hip_bfloat16*)pos;
    float m = 0.f;
    for (int i = t; i < 2048; i += 256) {
        float v = fabsf(b2f(pb[i]));
        if (v != v) v = 1e30f;
        m = fmaxf(m, v);
    }
    smax[t] = m;
    __syncthreads();
    for (int s = 128; s > 0; s >>= 1) {
        if (t < s) smax[t] = fmaxf(smax[t], smax[t + s]);
        __syncthreads();
    }
    const int* e32 = (const int*)ei;
    if (t < 128 && e32[2 * t + 1] != 0) anynz = 1;
    __syncthreads();
    if (t == 0) {
        flags[0] = (smax[0] > 1e6f) ? 1 : 0;
        flags[1] = anynz ? 0 : 1;
    }
}

// ---------------- input assembly: x0 bf16 [N,8] (pads 0) ----------------
__global__ void k_build_x0(const void* __restrict__ pos, const void* __restrict__ nrm,
                           unsigned short* __restrict__ x0b, const int* __restrict__ flags) {
    int f32 = flags[0];
    int i = blockIdx.x * blockDim.x + threadIdx.x;
    if (i >= NN) return;
#pragma unroll
    for (int j = 0; j < 3; j++) {
        x0b[i * 8 + j]     = f32 ? f2bu(((const float*)pos)[i * 3 + j])
                                 : ((const unsigned short*)pos)[i * 3 + j];
        x0b[i * 8 + 3 + j] = f32 ? f2bu(((const float*)nrm)[i * 3 + j])
                                 : ((const unsigned short*)nrm)[i * 3 + j];
    }
    x0b[i * 8 + 6] = 0;
    x0b[i * 8 + 7] = 0;
}

// ---------------- CSR build: two-level counting sort ----------------
__global__ void __launch_bounds__(256) k_sortA(const int* __restrict__ ei,
                                               int* __restrict__ counts,
                                               int* __restrict__ cntT,
                                               const int* __restrict__ flags) {
    __shared__ int hist[NBK];
    int i64 = flags[1];
    int t = threadIdx.x, w = blockIdx.x;
    for (int b = t; b < NBK; b += 256) hist[b] = 0;
    __syncthreads();
    int start = w * EPW, end = start + EPW;
    for (int e = start + t; e < end; e += 256) {
        int d = ldi(ei, NE + e, i64);
        atomicAdd(&counts[d], 1);
        atomicAdd(&hist[d >> 8], 1);
    }
    __syncthreads();
    for (int b = t; b < NBK; b += 256) cntT[b * SWG + w] = hist[b];
}

// -------- parallel 3-phase exclusive scan over two arrays --------
__global__ void __launch_bounds__(256) k_scan_local(const int* __restrict__ a0, int n0,
                                                    const int* __restrict__ a1, int n1,
                                                    int* __restrict__ o0, int* __restrict__ o1,
                                                    int* __restrict__ bsums, int nb0) {
    __shared__ int ws[4];
    int b = blockIdx.x;
    const int* a;
    int* o;
    int n, cbase;
    if (b < nb0) { a = a0; o = o0; n = n0; cbase = b * 256; }
    else { a = a1; o = o1; n = n1; cbase = (b - nb0) * 256; }
    int t = threadIdx.x, lane = t & 63, wid = t >> 6;
    int idx = cbase + t;
    int v = (idx < n) ? a[idx] : 0;
    int incl = v;
#pragma unroll
    for (int off = 1; off < 64; off <<= 1) {
        int nb = __shfl_up(incl, off, 64);
        if (lane >= off) incl += nb;
    }
    if (lane == 63) ws[wid] = incl;
    __syncthreads();
    int wpre = 0, tot = 0;
#pragma unroll
    for (int wi = 0; wi < 4; wi++) {
        int s = ws[wi];
        if (wi < wid) wpre += s;
        tot += s;
    }
    if (idx < n) o[idx] = wpre + incl - v;
    if (t == 0) bsums[b] = tot;
}

__global__ void __launch_bounds__(256) k_scan_sums(const int* __restrict__ bsums,
                                                   int* __restrict__ bpre,
                                                   int* __restrict__ o0, int n0,
                                                   int* __restrict__ o1, int n1) {
    __shared__ int ws[4];
    int blk = blockIdx.x;
    int t = threadIdx.x, lane = t & 63, wid = t >> 6;
    int base = blk * 196;
    int v = (t < 196) ? bsums[base + t] : 0;
    int incl = v;
#pragma unroll
    for (int off = 1; off < 64; off <<= 1) {
        int nb = __shfl_up(incl, off, 64);
        if (lane >= off) incl += nb;
    }
    if (lane == 63) ws[wid] = incl;
    __syncthreads();
    int wpre = 0, tot = 0;
#pragma unroll
    for (int wi = 0; wi < 4; wi++) {
        int s = ws[wi];
        if (wi < wid) wpre += s;
        tot += s;
    }
    if (t < 196) bpre[base + t] = wpre + incl - v;
    if (t == 0) {
        if (blk == 0) o0[n0] = tot;
        else o1[n1] = tot;
    }
}

__global__ void __launch_bounds__(256) k_scan_add(int* __restrict__ o0, int n0,
                                                  int* __restrict__ o1, int n1,
                                                  const int* __restrict__ bpre, int nb0) {
    int b = blockIdx.x;
    int* o;
    int n, cbase;
    if (b < nb0) { o = o0; n = n0; cbase = b * 256; }
    else { o = o1; n = n1; cbase = (b - nb0) * 256; }
    int idx = cbase + threadIdx.x;
    if (idx < n) o[idx] += bpre[b];
}

__global__ void __launch_bounds__(256) k_sortB(const int* __restrict__ ei,
                                               const int* __restrict__ base2,
                                               unsigned int* __restrict__ ebuck,
                                               const int* __restrict__ flags) {
    __shared__ int cur[NBK];
    int i64 = flags[1];
    int t = threadIdx.x, w = blockIdx.x;
    for (int b = t; b < NBK; b += 256) cur[b] = base2[b * SWG + w];
    __syncthreads();
    int start = w * EPW, end = start + EPW;
    for (int e = start + t; e < end; e += 256) {
        int s = ldi(ei, e, i64), d = ldi(ei, NE + e, i64);
        int slot = atomicAdd(&cur[d >> 8], 1);
        ebuck[slot] = (unsigned int)s | ((unsigned int)(d & 255) << 16);
    }
}

__global__ void __launch_bounds__(256) k_sortC(const unsigned int* __restrict__ ebuck,
                                               const int* __restrict__ base2,
                                               const int* __restrict__ offs,
                                               int* __restrict__ ssrc) {
    __shared__ int cur[256];
    int t = threadIdx.x, b = blockIdx.x;
    int gn = b * 256 + t;
    cur[t] = (gn < NN) ? offs[gn] : NE;
    __syncthreads();
    int bs = base2[b * SWG], be = base2[(b + 1) * SWG];
    for (int e = bs + t; e < be; e += 256) {
        unsigned int rec = ebuck[e];
        int slot = atomicAdd(&cur[(rec >> 16) & 255], 1);
        ssrc[slot] = (int)(rec & 0xffffu);
    }
}

// ---------------- p = x @ u  ->  p8 [N,8] fp32 (h<6 valid) ----------------
__global__ void __launch_bounds__(256) k_compute_p6(const unsigned short* __restrict__ x0b,
                                                    const void* __restrict__ u,
                                                    float* __restrict__ p8,
                                                    const int* __restrict__ flags) {
    int f32 = flags[0];
    int wave = (blockIdx.x * blockDim.x + threadIdx.x) >> 6;
    int lane = threadIdx.x & 63;
    if (wave >= NN) return;
    float acc[HH] = {0, 0, 0, 0, 0, 0};
    if (lane < 6) {
        float xv = u2f(x0b[(size_t)wave * 8 + lane]);
#pragma unroll
        for (int h = 0; h < HH; h++) acc[h] = xv * ldf(u, lane * HH + h, f32);
    }
#pragma unroll
    for (int off = 4; off > 0; off >>= 1) {
#pragma unroll
        for (int h = 0; h < HH; h++) acc[h] += __shfl_down(acc[h], off, 64);
    }
    if (lane == 0) {
#pragma unroll
        for (int h = 0; h < HH; h++) p8[(size_t)wave * 8 + h] = acc[h];
    }
}

__global__ void __launch_bounds__(256) k_compute_p128(const unsigned short* __restrict__ x,
                                                      const void* __restrict__ u,
                                                      float* __restrict__ p8,
                                                      const int* __restrict__ flags) {
    int f32 = flags[0];
    int wave = (blockIdx.x * blockDim.x + threadIdx.x) >> 6;
    int lane = threadIdx.x & 63;
    if (wave >= NN) return;
    unsigned int w = *(const unsigned int*)(x + (size_t)wave * 128 + 2 * lane);
    float x0 = lo2f(w);
    float x1 = hi2f(w);
    float acc[HH];
#pragma unroll
    for (int h = 0; h < HH; h++)
        acc[h] = x0 * ldf(u, (2 * lane) * HH + h, f32) + x1 * ldf(u, (2 * lane + 1) * HH + h, f32);
#pragma unroll
    for (int off = 32; off > 0; off >>= 1) {
#pragma unroll
        for (int h = 0; h < HH; h++) acc[h] += __shfl_down(acc[h], off, 64);
    }
    if (lane == 0) {
#pragma unroll
        for (int h = 0; h < HH; h++) p8[(size_t)wave * 8 + h] = acc[h];
    }
}

// ---------------- fused softmax + aggregation, CIN=128 (LDS-free) ----------
// r8 structure + q packed into 3 bf16-pair dwords (4 readlanes/edge).
__global__ void __launch_bounds__(256) k_agg128(const unsigned short* __restrict__ xb,
                                                const float* __restrict__ p8,
                                                const void* __restrict__ cvec,
                                                const int* __restrict__ ssrc,
                                                const int* __restrict__ offs,
                                                unsigned short* __restrict__ agg,
                                                const int* __restrict__ flags) {
    int f32 = flags[0];
    int lane = threadIdx.x & 63;
    int node = (blockIdx.x * blockDim.x + threadIdx.x) >> 6;
    if (node >= NN) return;
    int s0 = offs[node], s1 = offs[node + 1];
    int deg = s1 - s0;
    float scale = 1.0f / (float)(deg > 0 ? deg : 1);
    const float* pn = p8 + (size_t)node * 8;
    float pd[HH];
#pragma unroll
    for (int h = 0; h < HH; h++) pd[h] = pn[h] - ldf(cvec, h, f32);

    f32x2 a[HH] = {};
    for (int base = s0; base < s1; base += 64) {
        int cnt = (s1 - base < 64) ? (s1 - base) : 64;
        // ---- phase A: lane = edge; q packed bf16x2 x3 + row offset ----
        unsigned int pq0 = 0, pq1 = 0, pq2 = 0, rowElem = 0;
        {
            int e = base + lane;
            if (e < s1) {
                int j = ssrc[e];
                const float* pj = p8 + (size_t)j * 8;
                float4 pa = *(const float4*)pj;
                float2 pb = *(const float2*)(pj + 4);
                float t0 = pa.x - pd[0], t1 = pa.y - pd[1], t2 = pa.z - pd[2];
                float t3 = pa.w - pd[3], t4 = pb.x - pd[4], t5 = pb.y - pd[5];
                float mx = fmaxf(fmaxf(fmaxf(t0, t1), fmaxf(t2, t3)), fmaxf(t4, t5));
                float q0 = __expf(t0 - mx), q1 = __expf(t1 - mx), q2 = __expf(t2 - mx);
                float q3 = __expf(t3 - mx), q4 = __expf(t4 - mx), q5 = __expf(t5 - mx);
                float inv = 1.0f / (q0 + q1 + q2 + q3 + q4 + q5);
                pq0 = pk2(q0 * inv, q1 * inv);
                pq1 = pk2(q2 * inv, q3 * inv);
                pq2 = pk2(q4 * inv, q5 * inv);
                rowElem = (unsigned int)j * 128u;
            }
        }
        // ---- phase B: 4 readlanes/edge, gather dword, pk_fma ----
        int cnt8 = (cnt + 7) & ~7;
        for (int s = 0; s < cnt8; s += 8) {
            unsigned int xw[8];
#pragma unroll
            for (int u = 0; u < 8; u++) {
                unsigned int ro =
                    (unsigned int)__builtin_amdgcn_readlane((int)rowElem, s + u);
                xw[u] = *(const unsigned int*)(xb + (size_t)ro + 2 * lane);
            }
#pragma unroll
            for (int u = 0; u < 8; u++) {
                unsigned int w0 = (unsigned int)__builtin_amdgcn_readlane((int)pq0, s + u);
                unsigned int w1 = (unsigned int)__builtin_amdgcn_readlane((int)pq1, s + u);
                unsigned int w2 = (unsigned int)__builtin_amdgcn_readlane((int)pq2, s + u);
                float q0 = lo2f(w0), q1 = hi2f(w0);
                float q2 = lo2f(w1), q3 = hi2f(w1);
                float q4 = lo2f(w2), q5 = hi2f(w2);
                f32x2 xx;
                xx.x = lo2f(xw[u]);
                xx.y = hi2f(xw[u]);
                f32x2 v0 = q0, v1 = q1, v2 = q2, v3 = q3, v4 = q4, v5 = q5;
                a[0] = __builtin_elementwise_fma(v0, xx, a[0]);
                a[1] = __builtin_elementwise_fma(v1, xx, a[1]);
                a[2] = __builtin_elementwise_fma(v2, xx, a[2]);
                a[3] = __builtin_elementwise_fma(v3, xx, a[3]);
                a[4] = __builtin_elementwise_fma(v4, xx, a[4]);
                a[5] = __builtin_elementwise_fma(v5, xx, a[5]);
            }
        }
    }
    unsigned short* ar = agg + (size_t)node * 768;
#pragma unroll
    for (int h = 0; h < HH; h++) {
        *(unsigned int*)(ar + h * 128 + 2 * lane) = pk2(a[h].x * scale, a[h].y * scale);
    }
}

// ---------------- fused softmax + aggregation, CIN=6 (DMA staged) ---------
__global__ void __launch_bounds__(256) k_agg6(const unsigned short* __restrict__ xb,
                                              const float* __restrict__ p8,
                                              const void* __restrict__ cvec,
                                              const int* __restrict__ ssrc,
                                              const int* __restrict__ offs,
                                              float* __restrict__ agg,
                                              const int* __restrict__ flags) {
    __shared__ unsigned short stage6[4][64 * 8];     // 4 KB: 64 rows x 16 B
    __shared__ float qsf[4][64][8];                  // 8 KB: q[6] + rowbyte bits
    int f32 = flags[0];
    int wid = threadIdx.x >> 6, lane = threadIdx.x & 63;
    int node = (blockIdx.x * blockDim.x + threadIdx.x) >> 6;
    if (node >= NN) return;
    int s0 = offs[node], s1 = offs[node + 1];
    int deg = s1 - s0;
    float scale = 1.0f / (float)(deg > 0 ? deg : 1);
    const float* pn = p8 + (size_t)node * 8;
    float pd[HH];
#pragma unroll
    for (int h = 0; h < HH; h++) pd[h] = pn[h] - ldf(cvec, h, f32);

    float acc6 = 0.f;
    int hh6 = lane / 6, kk6 = lane - hh6 * 6;
    const char* xbase = (const char*)xb;
    for (int base = s0; base < s1; base += 64) {
        int cnt = (s1 - base < 64) ? (s1 - base) : 64;
        {
            int e = base + lane;
            float q0 = 0, q1 = 0, q2 = 0, q3 = 0, q4 = 0, q5 = 0;
            unsigned int rowByte = 0;
            if (e < s1) {
                int j = ssrc[e];
                const float* pj = p8 + (size_t)j * 8;
                float4 pa = *(const float4*)pj;
                float2 pb = *(const float2*)(pj + 4);
                float t0 = pa.x - pd[0], t1 = pa.y - pd[1], t2 = pa.z - pd[2];
                float t3 = pa.w - pd[3], t4 = pb.x - pd[4], t5 = pb.y - pd[5];
                float mx = fmaxf(fmaxf(fmaxf(t0, t1), fmaxf(t2, t3)), fmaxf(t4, t5));
                q0 = __expf(t0 - mx); q1 = __expf(t1 - mx); q2 = __expf(t2 - mx);
                q3 = __expf(t3 - mx); q4 = __expf(t4 - mx); q5 = __expf(t5 - mx);
                float inv = 1.0f / (q0 + q1 + q2 + q3 + q4 + q5);
                q0 *= inv; q1 *= inv; q2 *= inv; q3 *= inv; q4 *= inv; q5 *= inv;
                rowByte = (unsigned int)j * 16u;
            }
            float4 qa = {q0, q1, q2, q3};
            float4 qb = {q4, q5, __uint_as_float(rowByte), 0.f};
            *(float4*)&qsf[wid][lane][0] = qa;
            *(float4*)&qsf[wid][lane][4] = qb;
        }
        __builtin_amdgcn_sched_barrier(0);
#pragma unroll
        for (int t = 0; t < 4; t++) {
            int r = t * 16 + (lane >> 2);
            unsigned int rb = __float_as_uint(qsf[wid][r][6]);
            dma4(xbase + rb + (lane & 3) * 4, &stage6[wid][t * 128]);
        }
        __builtin_amdgcn_s_waitcnt(0x0f70);          // vmcnt(0) only
        __builtin_amdgcn_sched_barrier(0);
        if (lane < 36) {
            for (int s = 0; s < cnt; s++) {
                float qh = qsf[wid][s][hh6];
                float xv = u2f(stage6[wid][s * 8 + kk6]);
                acc6 = fmaf(qh, xv, acc6);
            }
        }
        __builtin_amdgcn_sched_barrier(0);
    }
    if (lane < 36) agg[(size_t)node * 36 + lane] = acc6 * scale;
}

// ---------------- fused weight repacks ----------------
// wstk1 fp32 [36,128]; wt2,wt3 bf16 [128,768] (B^T); wt4 bf16 [32,128]
// where wt4[n][k] = W4[k][n] for n<18 else 0.
__global__ void k_repack_all(const void* __restrict__ W1, const void* __restrict__ W2,
                             const void* __restrict__ W3, const void* __restrict__ W4,
                             float* __restrict__ wstk1, unsigned short* __restrict__ wt2,
                             unsigned short* __restrict__ wt3, unsigned short* __restrict__ wt4,
                             const int* __restrict__ flags) {
    int f32 = flags[0];
    int idx = blockIdx.x * blockDim.x + threadIdx.x;
    if (idx < 4608) {
        int f = idx & 127, m = idx >> 7;
        int h = m / 6, k = m - h * 6;
        wstk1[idx] = ldf(W1, k * 768 + h * 128 + f, f32);
        return;
    }
    idx -= 4608;
    if (idx < 98304) {
        int f = idx / 768, m = idx % 768;
        int h = m >> 7, kk = m & 127;
        wt2[idx] = f2bu(ldf(W2, kk * 768 + h * 128 + f, f32));
        return;
    }
    idx -= 98304;
    if (idx < 98304) {
        int f = idx / 768, m = idx % 768;
        int h = m >> 7, kk = m & 127;
        wt3[idx] = f2bu(ldf(W3, kk * 768 + h * 128 + f, f32));
        return;
    }
    idx -= 98304;
    if (idx < 4096) {
        int n = idx >> 7, k = idx & 127;
        wt4[idx] = (n < 18) ? f2bu(ldf(W4, k * 18 + n, f32)) : (unsigned short)0;
    }
}

// ---------------- layer-1 GEMM (fp32, K=36), writes bf16 x ----------------
__global__ void __launch_bounds__(256) k_gemm_f32(const float* __restrict__ A,
                                                  const float* __restrict__ B,
                                                  const void* __restrict__ bias,
                                                  unsigned short* __restrict__ C,
                                                  int M, int K, int relu,
                                                  const int* __restrict__ flags) {
    int f32 = flags[0];
    __shared__ float As[16][68];
    __shared__ float Bs[16][128];
    int tid = threadIdx.x;
    int tx = tid & 15;
    int ty = tid >> 4;
    int bm = blockIdx.x * 64;
    int arow = tid >> 2, ak = (tid & 3) * 4;
    int brow = tid >> 4, bcol = (tid & 15) * 8;
    float acc[4][8] = {};
    for (int k0 = 0; k0 < K; k0 += 16) {
        float4 av = {0, 0, 0, 0};
        int gr = bm + arow;
        if (gr < M && (k0 + ak) < K) av = *(const float4*)(A + (size_t)gr * K + k0 + ak);
        As[ak + 0][arow] = av.x;
        As[ak + 1][arow] = av.y;
        As[ak + 2][arow] = av.z;
        As[ak + 3][arow] = av.w;
        float4 bv0 = {0, 0, 0, 0}, bv1 = {0, 0, 0, 0};
        if ((k0 + brow) < K) {
            const float* bp = B + (size_t)(k0 + brow) * 128 + bcol;
            bv0 = *(const float4*)bp;
            bv1 = *(const float4*)(bp + 4);
        }
        *(float4*)&Bs[brow][bcol]     = bv0;
        *(float4*)&Bs[brow][bcol + 4] = bv1;
        __syncthreads();
#pragma unroll
        for (int kk = 0; kk < 16; kk++) {
            float a_[4], b_[8];
#pragma unroll
            for (int j = 0; j < 4; j++) a_[j] = As[kk][ty * 4 + j];
#pragma unroll
            for (int j = 0; j < 8; j++) b_[j] = Bs[kk][tx * 8 + j];
#pragma unroll
            for (int i = 0; i < 4; i++)
#pragma unroll
                for (int j = 0; j < 8; j++) acc[i][j] = fmaf(a_[i], b_[j], acc[i][j]);
        }
        __syncthreads();
    }
#pragma unroll
    for (int i = 0; i < 4; i++) {
        int row = bm + ty * 4 + i;
        if (row >= M) continue;
#pragma unroll
        for (int j = 0; j < 8; j++) {
            int col = tx * 8 + j;
            float v = acc[i][j] + ldf(bias, col, f32);
            if (relu) v = fmaxf(v, 0.f);
            C[(size_t)row * 128 + col] = f2bu(v);
        }
    }
}

// ---------------- MFMA GEMM: C[M,128] = A[M,768]bf16 @ Wt^T + bias, ReLU ----
__global__ void __launch_bounds__(256) k_gemm_mfma(const unsigned short* __restrict__ A,
                                                   const unsigned short* __restrict__ Bt,
                                                   const void* __restrict__ bias,
                                                   unsigned short* __restrict__ C,
                                                   int M, int relu,
                                                   const int* __restrict__ flags) {
    constexpr int K = 768, BK = 64;
    __shared__ unsigned short As[64][72];
    __shared__ unsigned short Bs[128][72];
    int f32 = flags[0];
    int tid = threadIdx.x;
    int lane = tid & 63, wid = tid >> 6;
    int wm = wid & 1, wn = wid >> 1;
    int bm = blockIdx.x * 64;
    int l15 = lane & 15, lq = lane >> 4;
    f32x4 acc[2][4] = {};

    for (int k0 = 0; k0 < K; k0 += BK) {
#pragma unroll
        for (int cc = 0; cc < 2; cc++) {
            int c = tid + cc * 256;
            int r = c >> 3, kc = (c & 7) * 8;
            bf16x8 av = {};
            int gr = bm + r;
            if (gr < M) av = *(const bf16x8*)(A + (size_t)gr * K + k0 + kc);
            *(bf16x8*)&As[r][kc] = av;
        }
#pragma unroll
        for (int cc = 0; cc < 4; cc++) {
            int c = tid + cc * 256;
            int n = c >> 3, kc = (c & 7) * 8;
            *(bf16x8*)&Bs[n][kc] = *(const bf16x8*)(Bt + (size_t)n * K + k0 + kc);
        }
        __syncthreads();
#pragma unroll
        for (int ks = 0; ks < BK; ks += 32) {
            int koff = ks + lq * 8;
            bf16x8 af[2], bfr[4];
#pragma unroll
            for (int tm = 0; tm < 2; tm++)
                af[tm] = *(const bf16x8*)&As[wm * 32 + tm * 16 + l15][koff];
#pragma unroll
            for (int tn = 0; tn < 4; tn++)
                bfr[tn] = *(const bf16x8*)&Bs[wn * 64 + tn * 16 + l15][koff];
#pragma unroll
            for (int tm = 0; tm < 2; tm++)
#pragma unroll
                for (int tn = 0; tn < 4; tn++)
                    acc[tm][tn] = __builtin_amdgcn_mfma_f32_16x16x32_bf16(
                        af[tm], bfr[tn], acc[tm][tn], 0, 0, 0);
        }
        __syncthreads();
    }
#pragma unroll
    for (int tm = 0; tm < 2; tm++) {
#pragma unroll
        for (int tn = 0; tn < 4; tn++) {
            int col = wn * 64 + tn * 16 + l15;
            float bv = ldf(bias, col, f32);
#pragma unroll
            for (int r = 0; r < 4; r++) {
                int row = bm + wm * 32 + tm * 16 + lq * 4 + r;
                if (row < M) {
                    float v = acc[tm][tn][r] + bv;
                    if (relu) v = fmaxf(v, 0.f);
                    C[(size_t)row * 128 + col] = f2bu(v);
                }
            }
        }
    }
}

// ---------------- y4 = x @ W4 : [N,128]bf16 @ [128,18] -> fp32 [N,20-pad] --
// 256 threads = 4 waves; wave handles 16 rows; N-tiles = 2 (cols 0..31).
__global__ void __launch_bounds__(256) k_y4(const unsigned short* __restrict__ xb,
                                            const unsigned short* __restrict__ wt4,
                                            float* __restrict__ y4) {
    int tid = threadIdx.x;
    int lane = tid & 63, wid = tid >> 6;
    int l15 = lane & 15, lq = lane >> 4;
    int bm = blockIdx.x * 64 + wid * 16;
    f32x4 acc[2] = {};
#pragma unroll
    for (int ks = 0; ks < 128; ks += 32) {
        int koff = ks + lq * 8;
        bf16x8 af = {};
        int row = bm + l15;
        if (row < NN) af = *(const bf16x8*)(xb + (size_t)row * 128 + koff);
        bf16x8 b0 = *(const bf16x8*)(wt4 + (0 * 16 + l15) * 128 + koff);
        bf16x8 b1 = *(const bf16x8*)(wt4 + (1 * 16 + l15) * 128 + koff);
        acc[0] = __builtin_amdgcn_mfma_f32_16x16x32_bf16(af, b0, acc[0], 0, 0, 0);
        acc[1] = __builtin_amdgcn_mfma_f32_16x16x32_bf16(af, b1, acc[1], 0, 0, 0);
    }
#pragma unroll
    for (int t = 0; t < 2; t++) {
#pragma unroll
        for (int r = 0; r < 4; r++) {
            int row = bm + lq * 4 + r;
            int col = t * 16 + l15;
            if (row < NN && col < 18) y4[(size_t)row * 20 + col] = acc[t][r];
        }
    }
}

// ---------------- final layer: lane-per-edge over y4 ----------------------
// out_i[f] = (1/deg) sum_e sum_h q_eh y4[src_e][3h+f] + b[f]
__global__ void __launch_bounds__(256) k_final_fast(const float* __restrict__ y4,
                                                    const float* __restrict__ p8,
                                                    const void* __restrict__ cvec,
                                                    const int* __restrict__ ssrc,
                                                    const int* __restrict__ offs,
                                                    const void* __restrict__ bias,
                                                    void* __restrict__ out,
                                                    const int* __restrict__ flags) {
    int f32 = flags[0];
    int lane = threadIdx.x & 63;
    int node = (blockIdx.x * blockDim.x + threadIdx.x) >> 6;
    if (node >= NN) return;
    int s0 = offs[node], s1 = offs[node + 1];
    int deg = s1 - s0;
    float scale = 1.0f / (float)(deg > 0 ? deg : 1);
    const float* pn = p8 + (size_t)node * 8;
    float pd[HH];
#pragma unroll
    for (int h = 0; h < HH; h++) pd[h] = pn[h] - ldf(cvec, h, f32);

    float f0 = 0, f1 = 0, f2 = 0;
    for (int base = s0; base < s1; base += 64) {
        int e = base + lane;
        if (e < s1) {
            int j = ssrc[e];
            const float* pj = p8 + (size_t)j * 8;
            float4 pa = *(const float4*)pj;
            float2 pb = *(const float2*)(pj + 4);
            float t0 = pa.x - pd[0], t1 = pa.y - pd[1], t2 = pa.z - pd[2];
            float t3 = pa.w - pd[3], t4 = pb.x - pd[4], t5 = pb.y - pd[5];
            float mx = fmaxf(fmaxf(fmaxf(t0, t1), fmaxf(t2, t3)), fmaxf(t4, t5));
            float q0 = __expf(t0 - mx), q1 = __expf(t1 - mx), q2 = __expf(t2 - mx);
            float q3 = __expf(t3 - mx), q4 = __expf(t4 - mx), q5 = __expf(t5 - mx);
            float inv = 1.0f / (q0 + q1 + q2 + q3 + q4 + q5);
            float qa[6] = {q0 * inv, q1 * inv, q2 * inv, q3 * inv, q4 * inv, q5 * inv};
            const float* yr = y4 + (size_t)j * 20;
            float yv[20];
            *(float4*)&yv[0]  = *(const float4*)(yr + 0);
            *(float4*)&yv[4]  = *(const float4*)(yr + 4);
            *(float4*)&yv[8]  = *(const float4*)(yr + 8);
            *(float4*)&yv[12] = *(const float4*)(yr + 12);
            *(float4*)&yv[16] = *(const float4*)(yr + 16);
#pragma unroll
            for (int h = 0; h < HH; h++) {
                f0 = fmaf(qa[h], yv[3 * h + 0], f0);
                f1 = fmaf(qa[h], yv[3 * h + 1], f1);
                f2 = fmaf(qa[h], yv[3 * h + 2], f2);
            }
        }
    }
#pragma unroll
    for (int off = 32; off > 0; off >>= 1) {
        f0 += __shfl_down(f0, off, 64);
        f1 += __shfl_down(f1, off, 64);
        f2 += __shfl_down(f2, off, 64);
    }
    if (lane == 0) {
        float r0 = f0 * scale + ldf(bias, 0, f32);
        float r1 = f1 * scale + ldf(bias, 1, f32);
        float r2 = f2 * scale + ldf(bias, 2, f32);
        if (f32) {
            float* o = (float*)out;
            o[(size_t)node * 3 + 0] = r0;
            o[(size_t)node * 3 + 1] = r1;
            o[(size_t)node * 3 + 2] = r2;
        } else {
            __hip_bfloat16* o = (__hip_bfloat16*)out;
            o[(size_t)node * 3 + 0] = __float2bfloat16(r0);
            o[(size_t)node * 3 + 1] = __float2bfloat16(r1);
            o[(size_t)node * 3 + 2] = __float2bfloat16(r2);
        }
    }
}

extern "C" void kernel_launch(void* const* d_in, const int* in_sizes, int n_in,
                              void* d_out, int out_size, void* d_ws, size_t ws_size,
                              hipStream_t stream) {
    (void)in_sizes; (void)n_in; (void)out_size; (void)ws_size;
    const void* pos = d_in[0];
    const void* nrm = d_in[1];
    const int* ei = (const int*)d_in[2];
    const void* W[4] = {d_in[3], d_in[7], d_in[11], d_in[15]};
    const void* U[4] = {d_in[4], d_in[8], d_in[12], d_in[16]};
    const void* Cc[4] = {d_in[5], d_in[9], d_in[13], d_in[17]};
    const void* Bb[4] = {d_in[6], d_in[10], d_in[14], d_in[18]};

    char* wp = (char*)d_ws;
    auto alloc = [&](size_t b) { void* r = (void*)wp; wp += (b + 255) & ~(size_t)255; return r; };
    unsigned short* xA  = (unsigned short*)alloc((size_t)NN * 128 * 2);
    unsigned short* xB  = (unsigned short*)alloc((size_t)NN * 128 * 2);
    unsigned short* x0b = (unsigned short*)alloc((size_t)NN * 8 * 2);
    float* p8     = (float*)alloc((size_t)NN * 8 * 4);
    float* y4     = (float*)alloc((size_t)NN * 20 * 4);
    int*   counts = (int*)alloc((size_t)NN * 4);
    int*   offs   = (int*)alloc((size_t)(NN + 1) * 4);
    int*   cntT   = (int*)alloc((size_t)NBK * SWG * 4);
    int*   base2  = (int*)alloc((size_t)(NBK * SWG + 1) * 4);
    int*   bsums  = (int*)alloc((size_t)512 * 4);
    int*   bpre   = (int*)alloc((size_t)512 * 4);
    int*   flags  = (int*)alloc(256);
    int*   ssrc   = (int*)alloc((size_t)NE * 4);
    unsigned int* ebuck = (unsigned int*)alloc((size_t)NE * 4);
    void*  aggv   = alloc((size_t)NN * 768 * 2);
    float* wstk1  = (float*)alloc((size_t)36 * 128 * 4);
    unsigned short* wt2 = (unsigned short*)alloc((size_t)128 * 768 * 2);
    unsigned short* wt3 = (unsigned short*)alloc((size_t)128 * 768 * 2);
    unsigned short* wt4 = (unsigned short*)alloc((size_t)32 * 128 * 2);
    unsigned short* agg_h = (unsigned short*)aggv;
    float* agg_f = (float*)aggv;

    const int NB = (NN + 255) / 256;
    const int NWB = (NN * 64 + 255) / 256;      // 256-thread wave-per-node grids
    const int GB = (NN + 63) / 64;

    k_detect<<<1, 256, 0, stream>>>(pos, ei, flags);
    hipMemsetAsync(counts, 0, (size_t)NN * 4, stream);
    k_sortA<<<SWG, 256, 0, stream>>>(ei, counts, cntT, flags);
    k_scan_local<<<392, 256, 0, stream>>>(counts, NN, cntT, NBK * SWG, offs, base2, bsums, 196);
    k_scan_sums<<<2, 256, 0, stream>>>(bsums, bpre, offs, NN, base2, NBK * SWG);
    k_scan_add<<<392, 256, 0, stream>>>(offs, NN, base2, NBK * SWG, bpre, 196);
    k_sortB<<<SWG, 256, 0, stream>>>(ei, base2, ebuck, flags);
    k_sortC<<<NBK, 256, 0, stream>>>(ebuck, base2, offs, ssrc);
    k_build_x0<<<NB, 256, 0, stream>>>(pos, nrm, x0b, flags);
    k_repack_all<<<(205312 + 255) / 256, 256, 0, stream>>>(W[0], W[1], W[2], W[3],
                                                           wstk1, wt2, wt3, wt4, flags);

    // ---- layer 1: 6 -> 128, relu ----
    k_compute_p6<<<NWB, 256, 0, stream>>>(x0b, U[0], p8, flags);
    k_agg6<<<NWB, 256, 0, stream>>>(x0b, p8, Cc[0], ssrc, offs, agg_f, flags);
    k_gemm_f32<<<GB, 256, 0, stream>>>(agg_f, wstk1, Bb[0], xA, NN, 36, 1, flags);

    // ---- layer 2: 128 -> 128, relu ----
    k_compute_p128<<<NWB, 256, 0, stream>>>(xA, U[1], p8, flags);
    k_agg128<<<NWB, 256, 0, stream>>>(xA, p8, Cc[1], ssrc, offs, agg_h, flags);
    k_gemm_mfma<<<GB, 256, 0, stream>>>(agg_h, wt2, Bb[1], xB, NN, 1, flags);

    // ---- layer 3: 128 -> 128, relu ----
    k_compute_p128<<<NWB, 256, 0, stream>>>(xB, U[2], p8, flags);
    k_agg128<<<NWB, 256, 0, stream>>>(xB, p8, Cc[2], ssrc, offs, agg_h, flags);
    k_gemm_mfma<<<GB, 256, 0, stream>>>(agg_h, wt3, Bb[2], xA, NN, 1, flags);

    // ---- layer 4: 128 -> 3 (transform-first) ----
    k_compute_p128<<<NWB, 256, 0, stream>>>(xA, U[3], p8, flags);
    k_y4<<<GB, 256, 0, stream>>>(xA, wt4, y4);
    k_final_fast<<<NWB, 256, 0, stream>>>(y4, p8, Cc[3], ssrc, offs, Bb[3], d_out, flags);
}

// Round 11
// 581.633 us; speedup vs baseline: 1.6452x; 1.1679x over previous
//
#include <hip/hip_runtime.h>
#include <hip/hip_bf16.h>

// FeaStConv x4 on MI355X.
//  (1) (xj-xi)@u = p[src]-p[dst] with p = x@u per node (p padded to [N,8]).
//  (2) layers 1-3: aggregate-then-transform (gather x 256B/edge -> Agg ->
//      dense MFMA GEMM). Layer 4: transform-first via k_y4p (y4 = x@W4 and
//      p = x@u in one MFMA kernel), final gathers 80B/edge.
// Round 11:
//  - agg128 phase B: scalar v_fma_f32 with SGPR q (readlane results stay
//    uniform; SALU unpack) — kills the f32x2 splat v_movs (r10's measured
//    ~52 instr/edge vs ~17 static pointed at 12 splat movs/edge).
//  - sort: global per-node atomics + counts memset removed; sortC does an
//    LDS counting sort per bucket and writes offs itself.
//  - k_y4p fuses layer-4 p into the y4 MFMA kernel.

#define HH 6
constexpr int NN = 50000;
constexpr int NE = 1600000;
constexpr int NBK = 196;           // buckets: dst>>8, covers 50176 nodes
constexpr int SWG = 256;           // sort workgroups
constexpr int EPW = NE / SWG;      // 6250 edges per sort wg

typedef __attribute__((ext_vector_type(8))) short bf16x8;
typedef __attribute__((ext_vector_type(4))) float f32x4;

static __device__ __forceinline__ float b2f(__hip_bfloat16 v) { return __bfloat162float(v); }
static __device__ __forceinline__ float u2f(unsigned short u) {
    return __uint_as_float(((unsigned int)u) << 16);
}
static __device__ __forceinline__ unsigned short f2bu(float v) {
    __hip_bfloat16 b = __float2bfloat16(v);
    return *reinterpret_cast<unsigned short*>(&b);
}
static __device__ __forceinline__ float lo2f(unsigned int w) {
    return __uint_as_float(w << 16);
}
static __device__ __forceinline__ float hi2f(unsigned int w) {
    return __uint_as_float(w & 0xffff0000u);
}
static __device__ __forceinline__ unsigned int pk2(float lo, float hi) {
    return ((unsigned int)f2bu(hi) << 16) | (unsigned int)f2bu(lo);
}
static __device__ __forceinline__ float ldf(const void* p, int i, int f32) {
    return f32 ? ((const float*)p)[i] : b2f(((const __hip_bfloat16*)p)[i]);
}
static __device__ __forceinline__ int ldi(const int* e32, int i, int i64) {
    return i64 ? e32[2 * i] : e32[i];
}
// async global->LDS: each lane copies 4B; lane i lands at ldst + i*4
static __device__ __forceinline__ void dma4(const void* g, void* l) {
    __builtin_amdgcn_global_load_lds(
        (const __attribute__((address_space(1))) void*)g,
        (__attribute__((address_space(3))) void*)l, 4, 0, 0);
}

// ---------------- dtype detection ----------------
__global__ void k_detect(const void* pos, const void* ei, int* flags) {
    __shared__ float smax[256];
    __shared__ int anynz;
    int t = threadIdx.x;
    if (t == 0) anynz = 0;
    const __hip_bfloat16* pb = (const __hip_bfloat16*)pos;
    float m = 0.f;
    for (int i = t; i < 2048; i += 256) {
        float v = fabsf(b2f(pb[i]));
        if (v != v) v = 1e30f;
        m = fmaxf(m, v);
    }
    smax[t] = m;
    __syncthreads();
    for (int s = 128; s > 0; s >>= 1) {
        if (t < s) smax[t] = fmaxf(smax[t], smax[t + s]);
        __syncthreads();
    }
    const int* e32 = (const int*)ei;
    if (t < 128 && e32[2 * t + 1] != 0) anynz = 1;
    __syncthreads();
    if (t == 0) {
        flags[0] = (smax[0] > 1e6f) ? 1 : 0;
        flags[1] = anynz ? 0 : 1;
    }
}

// ---------------- input assembly: x0 bf16 [N,8] (pads 0) ----------------
__global__ void k_build_x0(const void* __restrict__ pos, const void* __restrict__ nrm,
                           unsigned short* __restrict__ x0b, const int* __restrict__ flags) {
    int f32 = flags[0];
    int i = blockIdx.x * blockDim.x + threadIdx.x;
    if (i >= NN) return;
#pragma unroll
    for (int j = 0; j < 3; j++) {
        x0b[i * 8 + j]     = f32 ? f2bu(((const float*)pos)[i * 3 + j])
                                 : ((const unsigned short*)pos)[i * 3 + j];
        x0b[i * 8 + 3 + j] = f32 ? f2bu(((const float*)nrm)[i * 3 + j])
                                 : ((const unsigned short*)nrm)[i * 3 + j];
    }
    x0b[i * 8 + 6] = 0;
    x0b[i * 8 + 7] = 0;
}

// ---------------- CSR build: two-level counting sort ----------------
// stage A: per-(bucket,wg) histogram only (LDS atomics)
__global__ void __launch_bounds__(256) k_sortA(const int* __restrict__ ei,
                                               int* __restrict__ cntT,
                                               const int* __restrict__ flags) {
    __shared__ int hist[NBK];
    int i64 = flags[1];
    int t = threadIdx.x, w = blockIdx.x;
    for (int b = t; b < NBK; b += 256) hist[b] = 0;
    __syncthreads();
    int start = w * EPW, end = start + EPW;
    for (int e = start + t; e < end; e += 256) {
        int d = ldi(ei, NE + e, i64);
        atomicAdd(&hist[d >> 8], 1);
    }
    __syncthreads();
    for (int b = t; b < NBK; b += 256) cntT[b * SWG + w] = hist[b];
}

// -------- 3-phase exclusive scan over cntT[NBK*SWG] --------
__global__ void __launch_bounds__(256) k_scan_local(const int* __restrict__ a, int n,
                                                    int* __restrict__ o,
                                                    int* __restrict__ bsums) {
    __shared__ int ws[4];
    int b = blockIdx.x, t = threadIdx.x, lane = t & 63, wid = t >> 6;
    int idx = b * 256 + t;
    int v = (idx < n) ? a[idx] : 0;
    int incl = v;
#pragma unroll
    for (int off = 1; off < 64; off <<= 1) {
        int nb = __shfl_up(incl, off, 64);
        if (lane >= off) incl += nb;
    }
    if (lane == 63) ws[wid] = incl;
    __syncthreads();
    int wpre = 0, tot = 0;
#pragma unroll
    for (int wi = 0; wi < 4; wi++) {
        int s = ws[wi];
        if (wi < wid) wpre += s;
        tot += s;
    }
    if (idx < n) o[idx] = wpre + incl - v;
    if (t == 0) bsums[b] = tot;
}

__global__ void __launch_bounds__(256) k_scan_sums(const int* __restrict__ bsums,
                                                   int* __restrict__ bpre,
                                                   int* __restrict__ o, int n, int nb) {
    __shared__ int ws[4];
    int t = threadIdx.x, lane = t & 63, wid = t >> 6;
    int v = (t < nb) ? bsums[t] : 0;
    int incl = v;
#pragma unroll
    for (int off = 1; off < 64; off <<= 1) {
        int nbv = __shfl_up(incl, off, 64);
        if (lane >= off) incl += nbv;
    }
    if (lane == 63) ws[wid] = incl;
    __syncthreads();
    int wpre = 0, tot = 0;
#pragma unroll
    for (int wi = 0; wi < 4; wi++) {
        int s = ws[wi];
        if (wi < wid) wpre += s;
        tot += s;
    }
    if (t < nb) bpre[t] = wpre + incl - v;
    if (t == 0) o[n] = tot;
}

__global__ void __launch_bounds__(256) k_scan_add(int* __restrict__ o, int n,
                                                  const int* __restrict__ bpre) {
    int idx = blockIdx.x * 256 + threadIdx.x;
    if (idx < n) o[idx] += bpre[blockIdx.x];
}

// stage B: scatter packed {dloc,src} into per-(bucket,wg) contiguous ranges
__global__ void __launch_bounds__(256) k_sortB(const int* __restrict__ ei,
                                               const int* __restrict__ base2,
                                               unsigned int* __restrict__ ebuck,
                                               const int* __restrict__ flags) {
    __shared__ int cur[NBK];
    int i64 = flags[1];
    int t = threadIdx.x, w = blockIdx.x;
    for (int b = t; b < NBK; b += 256) cur[b] = base2[b * SWG + w];
    __syncthreads();
    int start = w * EPW, end = start + EPW;
    for (int e = start + t; e < end; e += 256) {
        int s = ldi(ei, e, i64), d = ldi(ei, NE + e, i64);
        int slot = atomicAdd(&cur[d >> 8], 1);
        ebuck[slot] = (unsigned int)s | ((unsigned int)(d & 255) << 16);
    }
}

// stage C: LDS counting sort within one bucket; writes offs + fine scatter
__global__ void __launch_bounds__(256) k_sortC(const unsigned int* __restrict__ ebuck,
                                               const int* __restrict__ base2,
                                               int* __restrict__ offs,
                                               int* __restrict__ ssrc) {
    __shared__ int cnt[256];
    __shared__ int ws[4];
    int t = threadIdx.x, b = blockIdx.x;
    int lane = t & 63, wid = t >> 6;
    cnt[t] = 0;
    __syncthreads();
    int bs = base2[b * SWG], be = base2[(b + 1) * SWG];
    for (int e = bs + t; e < be; e += 256)
        atomicAdd(&cnt[(ebuck[e] >> 16) & 255], 1);
    __syncthreads();
    int v = cnt[t];
    int incl = v;
#pragma unroll
    for (int off = 1; off < 64; off <<= 1) {
        int nb = __shfl_up(incl, off, 64);
        if (lane >= off) incl += nb;
    }
    if (lane == 63) ws[wid] = incl;
    __syncthreads();
    int wpre = 0;
#pragma unroll
    for (int wi = 0; wi < 4; wi++)
        if (wi < wid) wpre += ws[wi];
    int excl = wpre + incl - v;
    int gn = b * 256 + t;
    if (gn <= NN) offs[gn] = bs + excl;
    __syncthreads();
    cnt[t] = bs + excl;                // becomes the scatter cursor
    __syncthreads();
    for (int e = bs + t; e < be; e += 256) {
        unsigned int rec = ebuck[e];
        int slot = atomicAdd(&cnt[(rec >> 16) & 255], 1);
        ssrc[slot] = (int)(rec & 0xffffu);
    }
}

// ---------------- p = x @ u  ->  p8 [N,8] fp32 (h<6 valid) ----------------
__global__ void __launch_bounds__(256) k_compute_p6(const unsigned short* __restrict__ x0b,
                                                    const void* __restrict__ u,
                                                    float* __restrict__ p8,
                                                    const int* __restrict__ flags) {
    int f32 = flags[0];
    int wave = (blockIdx.x * blockDim.x + threadIdx.x) >> 6;
    int lane = threadIdx.x & 63;
    if (wave >= NN) return;
    float acc[HH] = {0, 0, 0, 0, 0, 0};
    if (lane < 6) {
        float xv = u2f(x0b[(size_t)wave * 8 + lane]);
#pragma unroll
        for (int h = 0; h < HH; h++) acc[h] = xv * ldf(u, lane * HH + h, f32);
    }
#pragma unroll
    for (int off = 4; off > 0; off >>= 1) {
#pragma unroll
        for (int h = 0; h < HH; h++) acc[h] += __shfl_down(acc[h], off, 64);
    }
    if (lane == 0) {
#pragma unroll
        for (int h = 0; h < HH; h++) p8[(size_t)wave * 8 + h] = acc[h];
    }
}

__global__ void __launch_bounds__(256) k_compute_p128(const unsigned short* __restrict__ x,
                                                      const void* __restrict__ u,
                                                      float* __restrict__ p8,
                                                      const int* __restrict__ flags) {
    int f32 = flags[0];
    int wave = (blockIdx.x * blockDim.x + threadIdx.x) >> 6;
    int lane = threadIdx.x & 63;
    if (wave >= NN) return;
    unsigned int w = *(const unsigned int*)(x + (size_t)wave * 128 + 2 * lane);
    float x0 = lo2f(w);
    float x1 = hi2f(w);
    float acc[HH];
#pragma unroll
    for (int h = 0; h < HH; h++)
        acc[h] = x0 * ldf(u, (2 * lane) * HH + h, f32) + x1 * ldf(u, (2 * lane + 1) * HH + h, f32);
#pragma unroll
    for (int off = 32; off > 0; off >>= 1) {
#pragma unroll
        for (int h = 0; h < HH; h++) acc[h] += __shfl_down(acc[h], off, 64);
    }
    if (lane == 0) {
#pragma unroll
        for (int h = 0; h < HH; h++) p8[(size_t)wave * 8 + h] = acc[h];
    }
}

// ---------------- fused softmax + aggregation, CIN=128 (LDS-free) ----------
// Phase B: uniform q via readlane -> SGPR, SALU unpack, 12 scalar v_fma_f32
// (one SGPR operand each). No packed splats.
__global__ void __launch_bounds__(256) k_agg128(const unsigned short* __restrict__ xb,
                                                const float* __restrict__ p8,
                                                const void* __restrict__ cvec,
                                                const int* __restrict__ ssrc,
                                                const int* __restrict__ offs,
                                                unsigned short* __restrict__ agg,
                                                const int* __restrict__ flags) {
    int f32 = flags[0];
    int lane = threadIdx.x & 63;
    int node = (blockIdx.x * blockDim.x + threadIdx.x) >> 6;
    if (node >= NN) return;
    int s0 = offs[node], s1 = offs[node + 1];
    int deg = s1 - s0;
    float scale = 1.0f / (float)(deg > 0 ? deg : 1);
    const float* pn = p8 + (size_t)node * 8;
    float pd[HH];
#pragma unroll
    for (int h = 0; h < HH; h++) pd[h] = pn[h] - ldf(cvec, h, f32);

    float a0[HH] = {}, a1[HH] = {};
    for (int base = s0; base < s1; base += 64) {
        int cnt = (s1 - base < 64) ? (s1 - base) : 64;
        // ---- phase A: lane = edge; q packed bf16x2 x3 + row offset ----
        unsigned int pq0 = 0, pq1 = 0, pq2 = 0, rowElem = 0;
        {
            int e = base + lane;
            if (e < s1) {
                int j = ssrc[e];
                const float* pj = p8 + (size_t)j * 8;
                float4 pa = *(const float4*)pj;
                float2 pb = *(const float2*)(pj + 4);
                float t0 = pa.x - pd[0], t1 = pa.y - pd[1], t2 = pa.z - pd[2];
                float t3 = pa.w - pd[3], t4 = pb.x - pd[4], t5 = pb.y - pd[5];
                float mx = fmaxf(fmaxf(fmaxf(t0, t1), fmaxf(t2, t3)), fmaxf(t4, t5));
                float q0 = __expf(t0 - mx), q1 = __expf(t1 - mx), q2 = __expf(t2 - mx);
                float q3 = __expf(t3 - mx), q4 = __expf(t4 - mx), q5 = __expf(t5 - mx);
                float inv = 1.0f / (q0 + q1 + q2 + q3 + q4 + q5);
                pq0 = pk2(q0 * inv, q1 * inv);
                pq1 = pk2(q2 * inv, q3 * inv);
                pq2 = pk2(q4 * inv, q5 * inv);
                rowElem = (unsigned int)j * 128u;
            }
        }
        // ---- phase B: uniform q + direct gather, 8 loads in flight ----
        int cnt8 = (cnt + 7) & ~7;
        for (int s = 0; s < cnt8; s += 8) {
            unsigned int xw[8];
#pragma unroll
            for (int u = 0; u < 8; u++) {
                unsigned int ro =
                    (unsigned int)__builtin_amdgcn_readlane((int)rowElem, s + u);
                xw[u] = *(const unsigned int*)(xb + (size_t)ro + 2 * lane);
            }
#pragma unroll
            for (int u = 0; u < 8; u++) {
                unsigned int w0 = (unsigned int)__builtin_amdgcn_readlane((int)pq0, s + u);
                unsigned int w1 = (unsigned int)__builtin_amdgcn_readlane((int)pq1, s + u);
                unsigned int w2 = (unsigned int)__builtin_amdgcn_readlane((int)pq2, s + u);
                float x0v = lo2f(xw[u]);
                float x1v = hi2f(xw[u]);
                float q0 = lo2f(w0), q1 = hi2f(w0);
                float q2 = lo2f(w1), q3 = hi2f(w1);
                float q4 = lo2f(w2), q5 = hi2f(w2);
                a0[0] = fmaf(q0, x0v, a0[0]);
                a1[0] = fmaf(q0, x1v, a1[0]);
                a0[1] = fmaf(q1, x0v, a0[1]);
                a1[1] = fmaf(q1, x1v, a1[1]);
                a0[2] = fmaf(q2, x0v, a0[2]);
                a1[2] = fmaf(q2, x1v, a1[2]);
                a0[3] = fmaf(q3, x0v, a0[3]);
                a1[3] = fmaf(q3, x1v, a1[3]);
                a0[4] = fmaf(q4, x0v, a0[4]);
                a1[4] = fmaf(q4, x1v, a1[4]);
                a0[5] = fmaf(q5, x0v, a0[5]);
                a1[5] = fmaf(q5, x1v, a1[5]);
            }
        }
    }
    unsigned short* ar = agg + (size_t)node * 768;
#pragma unroll
    for (int h = 0; h < HH; h++) {
        *(unsigned int*)(ar + h * 128 + 2 * lane) = pk2(a0[h] * scale, a1[h] * scale);
    }
}

// ---------------- fused softmax + aggregation, CIN=6 (DMA staged) ---------
__global__ void __launch_bounds__(256) k_agg6(const unsigned short* __restrict__ xb,
                                              const float* __restrict__ p8,
                                              const void* __restrict__ cvec,
                                              const int* __restrict__ ssrc,
                                              const int* __restrict__ offs,
                                              float* __restrict__ agg,
                                              const int* __restrict__ flags) {
    __shared__ unsigned short stage6[4][64 * 8];     // 4 KB: 64 rows x 16 B
    __shared__ float qsf[4][64][8];                  // 8 KB: q[6] + rowbyte bits
    int f32 = flags[0];
    int wid = threadIdx.x >> 6, lane = threadIdx.x & 63;
    int node = (blockIdx.x * blockDim.x + threadIdx.x) >> 6;
    if (node >= NN) return;
    int s0 = offs[node], s1 = offs[node + 1];
    int deg = s1 - s0;
    float scale = 1.0f / (float)(deg > 0 ? deg : 1);
    const float* pn = p8 + (size_t)node * 8;
    float pd[HH];
#pragma unroll
    for (int h = 0; h < HH; h++) pd[h] = pn[h] - ldf(cvec, h, f32);

    float acc6 = 0.f;
    int hh6 = lane / 6, kk6 = lane - hh6 * 6;
    const char* xbase = (const char*)xb;
    for (int base = s0; base < s1; base += 64) {
        int cnt = (s1 - base < 64) ? (s1 - base) : 64;
        {
            int e = base + lane;
            float q0 = 0, q1 = 0, q2 = 0, q3 = 0, q4 = 0, q5 = 0;
            unsigned int rowByte = 0;
            if (e < s1) {
                int j = ssrc[e];
                const float* pj = p8 + (size_t)j * 8;
                float4 pa = *(const float4*)pj;
                float2 pb = *(const float2*)(pj + 4);
                float t0 = pa.x - pd[0], t1 = pa.y - pd[1], t2 = pa.z - pd[2];
                float t3 = pa.w - pd[3], t4 = pb.x - pd[4], t5 = pb.y - pd[5];
                float mx = fmaxf(fmaxf(fmaxf(t0, t1), fmaxf(t2, t3)), fmaxf(t4, t5));
                q0 = __expf(t0 - mx); q1 = __expf(t1 - mx); q2 = __expf(t2 - mx);
                q3 = __expf(t3 - mx); q4 = __expf(t4 - mx); q5 = __expf(t5 - mx);
                float inv = 1.0f / (q0 + q1 + q2 + q3 + q4 + q5);
                q0 *= inv; q1 *= inv; q2 *= inv; q3 *= inv; q4 *= inv; q5 *= inv;
                rowByte = (unsigned int)j * 16u;
            }
            float4 qa = {q0, q1, q2, q3};
            float4 qb = {q4, q5, __uint_as_float(rowByte), 0.f};
            *(float4*)&qsf[wid][lane][0] = qa;
            *(float4*)&qsf[wid][lane][4] = qb;
        }
        __builtin_amdgcn_sched_barrier(0);
#pragma unroll
        for (int t = 0; t < 4; t++) {
            int r = t * 16 + (lane >> 2);
            unsigned int rb = __float_as_uint(qsf[wid][r][6]);
            dma4(xbase + rb + (lane & 3) * 4, &stage6[wid][t * 128]);
        }
        __builtin_amdgcn_s_waitcnt(0x0f70);          // vmcnt(0) only
        __builtin_amdgcn_sched_barrier(0);
        if (lane < 36) {
            for (int s = 0; s < cnt; s++) {
                float qh = qsf[wid][s][hh6];
                float xv = u2f(stage6[wid][s * 8 + kk6]);
                acc6 = fmaf(qh, xv, acc6);
            }
        }
        __builtin_amdgcn_sched_barrier(0);
    }
    if (lane < 36) agg[(size_t)node * 36 + lane] = acc6 * scale;
}

// ---------------- fused weight repacks ----------------
// wstk1 fp32 [36,128]; wt2,wt3 bf16 [128,768] (B^T); wt4 bf16 [32,128];
// u4 bf16 [16,128] where u4[n][k] = U4[k*6+n] for n<6 else 0.
__global__ void k_repack_all(const void* __restrict__ W1, const void* __restrict__ W2,
                             const void* __restrict__ W3, const void* __restrict__ W4,
                             const void* __restrict__ U4,
                             float* __restrict__ wstk1, unsigned short* __restrict__ wt2,
                             unsigned short* __restrict__ wt3, unsigned short* __restrict__ wt4,
                             unsigned short* __restrict__ u4,
                             const int* __restrict__ flags) {
    int f32 = flags[0];
    int idx = blockIdx.x * blockDim.x + threadIdx.x;
    if (idx < 4608) {
        int f = idx & 127, m = idx >> 7;
        int h = m / 6, k = m - h * 6;
        wstk1[idx] = ldf(W1, k * 768 + h * 128 + f, f32);
        return;
    }
    idx -= 4608;
    if (idx < 98304) {
        int f = idx / 768, m = idx % 768;
        int h = m >> 7, kk = m & 127;
        wt2[idx] = f2bu(ldf(W2, kk * 768 + h * 128 + f, f32));
        return;
    }
    idx -= 98304;
    if (idx < 98304) {
        int f = idx / 768, m = idx % 768;
        int h = m >> 7, kk = m & 127;
        wt3[idx] = f2bu(ldf(W3, kk * 768 + h * 128 + f, f32));
        return;
    }
    idx -= 98304;
    if (idx < 4096) {
        int n = idx >> 7, k = idx & 127;
        wt4[idx] = (n < 18) ? f2bu(ldf(W4, k * 18 + n, f32)) : (unsigned short)0;
        return;
    }
    idx -= 4096;
    if (idx < 2048) {
        int n = idx >> 7, k = idx & 127;
        u4[idx] = (n < 6) ? f2bu(ldf(U4, k * 6 + n, f32)) : (unsigned short)0;
    }
}

// ---------------- layer-1 GEMM (fp32, K=36), writes bf16 x ----------------
__global__ void __launch_bounds__(256) k_gemm_f32(const float* __restrict__ A,
                                                  const float* __restrict__ B,
                                                  const void* __restrict__ bias,
                                                  unsigned short* __restrict__ C,
                                                  int M, int K, int relu,
                                                  const int* __restrict__ flags) {
    int f32 = flags[0];
    __shared__ float As[16][68];
    __shared__ float Bs[16][128];
    int tid = threadIdx.x;
    int tx = tid & 15;
    int ty = tid >> 4;
    int bm = blockIdx.x * 64;
    int arow = tid >> 2, ak = (tid & 3) * 4;
    int brow = tid >> 4, bcol = (tid & 15) * 8;
    float acc[4][8] = {};
    for (int k0 = 0; k0 < K; k0 += 16) {
        float4 av = {0, 0, 0, 0};
        int gr = bm + arow;
        if (gr < M && (k0 + ak) < K) av = *(const float4*)(A + (size_t)gr * K + k0 + ak);
        As[ak + 0][arow] = av.x;
        As[ak + 1][arow] = av.y;
        As[ak + 2][arow] = av.z;
        As[ak + 3][arow] = av.w;
        float4 bv0 = {0, 0, 0, 0}, bv1 = {0, 0, 0, 0};
        if ((k0 + brow) < K) {
            const float* bp = B + (size_t)(k0 + brow) * 128 + bcol;
            bv0 = *(const float4*)bp;
            bv1 = *(const float4*)(bp + 4);
        }
        *(float4*)&Bs[brow][bcol]     = bv0;
        *(float4*)&Bs[brow][bcol + 4] = bv1;
        __syncthreads();
#pragma unroll
        for (int kk = 0; kk < 16; kk++) {
            float a_[4], b_[8];
#pragma unroll
            for (int j = 0; j < 4; j++) a_[j] = As[kk][ty * 4 + j];
#pragma unroll
            for (int j = 0; j < 8; j++) b_[j] = Bs[kk][tx * 8 + j];
#pragma unroll
            for (int i = 0; i < 4; i++)
#pragma unroll
                for (int j = 0; j < 8; j++) acc[i][j] = fmaf(a_[i], b_[j], acc[i][j]);
        }
        __syncthreads();
    }
#pragma unroll
    for (int i = 0; i < 4; i++) {
        int row = bm + ty * 4 + i;
        if (row >= M) continue;
#pragma unroll
        for (int j = 0; j < 8; j++) {
            int col = tx * 8 + j;
            float v = acc[i][j] + ldf(bias, col, f32);
            if (relu) v = fmaxf(v, 0.f);
            C[(size_t)row * 128 + col] = f2bu(v);
        }
    }
}

// ---------------- MFMA GEMM: C[M,128] = A[M,768]bf16 @ Wt^T + bias, ReLU ----
__global__ void __launch_bounds__(256) k_gemm_mfma(const unsigned short* __restrict__ A,
                                                   const unsigned short* __restrict__ Bt,
                                                   const void* __restrict__ bias,
                                                   unsigned short* __restrict__ C,
                                                   int M, int relu,
                                                   const int* __restrict__ flags) {
    constexpr int K = 768, BK = 64;
    __shared__ unsigned short As[64][72];
    __shared__ unsigned short Bs[128][72];
    int f32 = flags[0];
    int tid = threadIdx.x;
    int lane = tid & 63, wid = tid >> 6;
    int wm = wid & 1, wn = wid >> 1;
    int bm = blockIdx.x * 64;
    int l15 = lane & 15, lq = lane >> 4;
    f32x4 acc[2][4] = {};

    for (int k0 = 0; k0 < K; k0 += BK) {
#pragma unroll
        for (int cc = 0; cc < 2; cc++) {
            int c = tid + cc * 256;
            int r = c >> 3, kc = (c & 7) * 8;
            bf16x8 av = {};
            int gr = bm + r;
            if (gr < M) av = *(const bf16x8*)(A + (size_t)gr * K + k0 + kc);
            *(bf16x8*)&As[r][kc] = av;
        }
#pragma unroll
        for (int cc = 0; cc < 4; cc++) {
            int c = tid + cc * 256;
            int n = c >> 3, kc = (c & 7) * 8;
            *(bf16x8*)&Bs[n][kc] = *(const bf16x8*)(Bt + (size_t)n * K + k0 + kc);
        }
        __syncthreads();
#pragma unroll
        for (int ks = 0; ks < BK; ks += 32) {
            int koff = ks + lq * 8;
            bf16x8 af[2], bfr[4];
#pragma unroll
            for (int tm = 0; tm < 2; tm++)
                af[tm] = *(const bf16x8*)&As[wm * 32 + tm * 16 + l15][koff];
#pragma unroll
            for (int tn = 0; tn < 4; tn++)
                bfr[tn] = *(const bf16x8*)&Bs[wn * 64 + tn * 16 + l15][koff];
#pragma unroll
            for (int tm = 0; tm < 2; tm++)
#pragma unroll
                for (int tn = 0; tn < 4; tn++)
                    acc[tm][tn] = __builtin_amdgcn_mfma_f32_16x16x32_bf16(
                        af[tm], bfr[tn], acc[tm][tn], 0, 0, 0);
        }
        __syncthreads();
    }
#pragma unroll
    for (int tm = 0; tm < 2; tm++) {
#pragma unroll
        for (int tn = 0; tn < 4; tn++) {
            int col = wn * 64 + tn * 16 + l15;
            float bv = ldf(bias, col, f32);
#pragma unroll
            for (int r = 0; r < 4; r++) {
                int row = bm + wm * 32 + tm * 16 + lq * 4 + r;
                if (row < M) {
                    float v = acc[tm][tn][r] + bv;
                    if (relu) v = fmaxf(v, 0.f);
                    C[(size_t)row * 128 + col] = f2bu(v);
                }
            }
        }
    }
}

// ---------------- layer-4: y4 = x@W4 AND p = x@u in one MFMA kernel -------
__global__ void __launch_bounds__(256) k_y4p(const unsigned short* __restrict__ xb,
                                             const unsigned short* __restrict__ wt4,
                                             const unsigned short* __restrict__ u4,
                                             float* __restrict__ y4,
                                             float* __restrict__ p8) {
    int tid = threadIdx.x;
    int lane = tid & 63, wid = tid >> 6;
    int l15 = lane & 15, lq = lane >> 4;
    int bm = blockIdx.x * 64 + wid * 16;
    f32x4 acc[2] = {};
    f32x4 accp = {};
#pragma unroll
    for (int ks = 0; ks < 128; ks += 32) {
        int koff = ks + lq * 8;
        bf16x8 af = {};
        int row = bm + l15;
        if (row < NN) af = *(const bf16x8*)(xb + (size_t)row * 128 + koff);
        bf16x8 b0 = *(const bf16x8*)(wt4 + (0 * 16 + l15) * 128 + koff);
        bf16x8 b1 = *(const bf16x8*)(wt4 + (1 * 16 + l15) * 128 + koff);
        bf16x8 bu = *(const bf16x8*)(u4 + l15 * 128 + koff);
        acc[0] = __builtin_amdgcn_mfma_f32_16x16x32_bf16(af, b0, acc[0], 0, 0, 0);
        acc[1] = __builtin_amdgcn_mfma_f32_16x16x32_bf16(af, b1, acc[1], 0, 0, 0);
        accp = __builtin_amdgcn_mfma_f32_16x16x32_bf16(af, bu, accp, 0, 0, 0);
    }
#pragma unroll
    for (int t = 0; t < 2; t++) {
#pragma unroll
        for (int r = 0; r < 4; r++) {
            int row = bm + lq * 4 + r;
            int col = t * 16 + l15;
            if (row < NN && col < 18) y4[(size_t)row * 20 + col] = acc[t][r];
        }
    }
#pragma unroll
    for (int r = 0; r < 4; r++) {
        int row = bm + lq * 4 + r;
        if (row < NN && l15 < 6) p8[(size_t)row * 8 + l15] = accp[r];
    }
}

// ---------------- final layer: lane-per-edge over y4 ----------------------
__global__ void __launch_bounds__(256) k_final_fast(const float* __restrict__ y4,
                                                    const float* __restrict__ p8,
                                                    const void* __restrict__ cvec,
                                                    const int* __restrict__ ssrc,
                                                    const int* __restrict__ offs,
                                                    const void* __restrict__ bias,
                                                    void* __restrict__ out,
                                                    const int* __restrict__ flags) {
    int f32 = flags[0];
    int lane = threadIdx.x & 63;
    int node = (blockIdx.x * blockDim.x + threadIdx.x) >> 6;
    if (node >= NN) return;
    int s0 = offs[node], s1 = offs[node + 1];
    int deg = s1 - s0;
    float scale = 1.0f / (float)(deg > 0 ? deg : 1);
    const float* pn = p8 + (size_t)node * 8;
    float pd[HH];
#pragma unroll
    for (int h = 0; h < HH; h++) pd[h] = pn[h] - ldf(cvec, h, f32);

    float f0 = 0, f1 = 0, f2 = 0;
    for (int base = s0; base < s1; base += 64) {
        int e = base + lane;
        if (e < s1) {
            int j = ssrc[e];
            const float* pj = p8 + (size_t)j * 8;
            float4 pa = *(const float4*)pj;
            float2 pb = *(const float2*)(pj + 4);
            float t0 = pa.x - pd[0], t1 = pa.y - pd[1], t2 = pa.z - pd[2];
            float t3 = pa.w - pd[3], t4 = pb.x - pd[4], t5 = pb.y - pd[5];
            float mx = fmaxf(fmaxf(fmaxf(t0, t1), fmaxf(t2, t3)), fmaxf(t4, t5));
            float q0 = __expf(t0 - mx), q1 = __expf(t1 - mx), q2 = __expf(t2 - mx);
            float q3 = __expf(t3 - mx), q4 = __expf(t4 - mx), q5 = __expf(t5 - mx);
            float inv = 1.0f / (q0 + q1 + q2 + q3 + q4 + q5);
            float qa[6] = {q0 * inv, q1 * inv, q2 * inv, q3 * inv, q4 * inv, q5 * inv};
            const float* yr = y4 + (size_t)j * 20;
            float yv[20];
            *(float4*)&yv[0]  = *(const float4*)(yr + 0);
            *(float4*)&yv[4]  = *(const float4*)(yr + 4);
            *(float4*)&yv[8]  = *(const float4*)(yr + 8);
            *(float4*)&yv[12] = *(const float4*)(yr + 12);
            *(float4*)&yv[16] = *(const float4*)(yr + 16);
#pragma unroll
            for (int h = 0; h < HH; h++) {
                f0 = fmaf(qa[h], yv[3 * h + 0], f0);
                f1 = fmaf(qa[h], yv[3 * h + 1], f1);
                f2 = fmaf(qa[h], yv[3 * h + 2], f2);
            }
        }
    }
#pragma unroll
    for (int off = 32; off > 0; off >>= 1) {
        f0 += __shfl_down(f0, off, 64);
        f1 += __shfl_down(f1, off, 64);
        f2 += __shfl_down(f2, off, 64);
    }
    if (lane == 0) {
        float r0 = f0 * scale + ldf(bias, 0, f32);
        float r1 = f1 * scale + ldf(bias, 1, f32);
        float r2 = f2 * scale + ldf(bias, 2, f32);
        if (f32) {
            float* o = (float*)out;
            o[(size_t)node * 3 + 0] = r0;
            o[(size_t)node * 3 + 1] = r1;
            o[(size_t)node * 3 + 2] = r2;
        } else {
            __hip_bfloat16* o = (__hip_bfloat16*)out;
            o[(size_t)node * 3 + 0] = __float2bfloat16(r0);
            o[(size_t)node * 3 + 1] = __float2bfloat16(r1);
            o[(size_t)node * 3 + 2] = __float2bfloat16(r2);
        }
    }
}

extern "C" void kernel_launch(void* const* d_in, const int* in_sizes, int n_in,
                              void* d_out, int out_size, void* d_ws, size_t ws_size,
                              hipStream_t stream) {
    (void)in_sizes; (void)n_in; (void)out_size; (void)ws_size;
    const void* pos = d_in[0];
    const void* nrm = d_in[1];
    const int* ei = (const int*)d_in[2];
    const void* W[4] = {d_in[3], d_in[7], d_in[11], d_in[15]};
    const void* U[4] = {d_in[4], d_in[8], d_in[12], d_in[16]};
    const void* Cc[4] = {d_in[5], d_in[9], d_in[13], d_in[17]};
    const void* Bb[4] = {d_in[6], d_in[10], d_in[14], d_in[18]};

    char* wp = (char*)d_ws;
    auto alloc = [&](size_t b) { void* r = (void*)wp; wp += (b + 255) & ~(size_t)255; return r; };
    unsigned short* xA  = (unsigned short*)alloc((size_t)NN * 128 * 2);
    unsigned short* xB  = (unsigned short*)alloc((size_t)NN * 128 * 2);
    unsigned short* x0b = (unsigned short*)alloc((size_t)NN * 8 * 2);
    float* p8     = (float*)alloc((size_t)NN * 8 * 4);
    float* y4     = (float*)alloc((size_t)NN * 20 * 4);
    int*   offs   = (int*)alloc((size_t)(NN + 1) * 4);
    int*   cntT   = (int*)alloc((size_t)NBK * SWG * 4);
    int*   base2  = (int*)alloc((size_t)(NBK * SWG + 1) * 4);
    int*   bsums  = (int*)alloc((size_t)256 * 4);
    int*   bpre   = (int*)alloc((size_t)256 * 4);
    int*   flags  = (int*)alloc(256);
    int*   ssrc   = (int*)alloc((size_t)NE * 4);
    unsigned int* ebuck = (unsigned int*)alloc((size_t)NE * 4);
    void*  aggv   = alloc((size_t)NN * 768 * 2);
    float* wstk1  = (float*)alloc((size_t)36 * 128 * 4);
    unsigned short* wt2 = (unsigned short*)alloc((size_t)128 * 768 * 2);
    unsigned short* wt3 = (unsigned short*)alloc((size_t)128 * 768 * 2);
    unsigned short* wt4 = (unsigned short*)alloc((size_t)32 * 128 * 2);
    unsigned short* u4  = (unsigned short*)alloc((size_t)16 * 128 * 2);
    unsigned short* agg_h = (unsigned short*)aggv;
    float* agg_f = (float*)aggv;

    const int NB = (NN + 255) / 256;
    const int NWB = (NN * 64 + 255) / 256;      // 256-thread wave-per-node grids
    const int GB = (NN + 63) / 64;
    const int NSC = NBK * SWG;                   // 50176

    k_detect<<<1, 256, 0, stream>>>(pos, ei, flags);
    k_sortA<<<SWG, 256, 0, stream>>>(ei, cntT, flags);
    k_scan_local<<<NBK, 256, 0, stream>>>(cntT, NSC, base2, bsums);
    k_scan_sums<<<1, 256, 0, stream>>>(bsums, bpre, base2, NSC, NBK);
    k_scan_add<<<NBK, 256, 0, stream>>>(base2, NSC, bpre);
    k_sortB<<<SWG, 256, 0, stream>>>(ei, base2, ebuck, flags);
    k_sortC<<<NBK, 256, 0, stream>>>(ebuck, base2, offs, ssrc);
    k_build_x0<<<NB, 256, 0, stream>>>(pos, nrm, x0b, flags);
    k_repack_all<<<(207360 + 255) / 256, 256, 0, stream>>>(W[0], W[1], W[2], W[3], U[3],
                                                           wstk1, wt2, wt3, wt4, u4, flags);

    // ---- layer 1: 6 -> 128, relu ----
    k_compute_p6<<<NWB, 256, 0, stream>>>(x0b, U[0], p8, flags);
    k_agg6<<<NWB, 256, 0, stream>>>(x0b, p8, Cc[0], ssrc, offs, agg_f, flags);
    k_gemm_f32<<<GB, 256, 0, stream>>>(agg_f, wstk1, Bb[0], xA, NN, 36, 1, flags);

    // ---- layer 2: 128 -> 128, relu ----
    k_compute_p128<<<NWB, 256, 0, stream>>>(xA, U[1], p8, flags);
    k_agg128<<<NWB, 256, 0, stream>>>(xA, p8, Cc[1], ssrc, offs, agg_h, flags);
    k_gemm_mfma<<<GB, 256, 0, stream>>>(agg_h, wt2, Bb[1], xB, NN, 1, flags);

    // ---- layer 3: 128 -> 128, relu ----
    k_compute_p128<<<NWB, 256, 0, stream>>>(xB, U[2], p8, flags);
    k_agg128<<<NWB, 256, 0, stream>>>(xB, p8, Cc[2], ssrc, offs, agg_h, flags);
    k_gemm_mfma<<<GB, 256, 0, stream>>>(agg_h, wt3, Bb[2], xA, NN, 1, flags);

    // ---- layer 4: 128 -> 3 (transform-first; y4 + p fused) ----
    k_y4p<<<GB, 256, 0, stream>>>(xA, wt4, u4, y4, p8);
    k_final_fast<<<NWB, 256, 0, stream>>>(y4, p8, Cc[3], ssrc, offs, Bb[3], d_out, flags);
}

// Round 12
// 563.169 us; speedup vs baseline: 1.6992x; 1.0328x over previous
//
#include <hip/hip_runtime.h>
#include <hip/hip_bf16.h>

// FeaStConv x4 on MI355X.
//  (1) (xj-xi)@u = p[src]-p[dst] with p = x@u per node (p padded to [N,8]).
//  (2) layers 1-3: aggregate-then-transform (gather x 256B/edge -> Agg ->
//      dense MFMA GEMM). Layer 4: transform-first via k_y4p (y4 = x@W4 and
//      p = x@u in one MFMA kernel), final gathers 80B/edge.
// Round 12: agg128 q-broadcast via LDS fp32 (32B/edge entry; phase B does
// broadcast ds_read_b128+b64, zero unpack VALU) instead of 3 readlanes +
// 6 shift/and unpacks. rowElem keeps its readlane (scalar -> saddr fold).
// Per-edge issues ~22 -> ~17. Everything else unchanged from r11.

#define HH 6
constexpr int NN = 50000;
constexpr int NE = 1600000;
constexpr int NBK = 196;           // buckets: dst>>8, covers 50176 nodes
constexpr int SWG = 256;           // sort workgroups
constexpr int EPW = NE / SWG;      // 6250 edges per sort wg

typedef __attribute__((ext_vector_type(8))) short bf16x8;
typedef __attribute__((ext_vector_type(4))) float f32x4;

static __device__ __forceinline__ float b2f(__hip_bfloat16 v) { return __bfloat162float(v); }
static __device__ __forceinline__ float u2f(unsigned short u) {
    return __uint_as_float(((unsigned int)u) << 16);
}
static __device__ __forceinline__ unsigned short f2bu(float v) {
    __hip_bfloat16 b = __float2bfloat16(v);
    return *reinterpret_cast<unsigned short*>(&b);
}
static __device__ __forceinline__ float lo2f(unsigned int w) {
    return __uint_as_float(w << 16);
}
static __device__ __forceinline__ float hi2f(unsigned int w) {
    return __uint_as_float(w & 0xffff0000u);
}
static __device__ __forceinline__ unsigned int pk2(float lo, float hi) {
    return ((unsigned int)f2bu(hi) << 16) | (unsigned int)f2bu(lo);
}
static __device__ __forceinline__ float ldf(const void* p, int i, int f32) {
    return f32 ? ((const float*)p)[i] : b2f(((const __hip_bfloat16*)p)[i]);
}
static __device__ __forceinline__ int ldi(const int* e32, int i, int i64) {
    return i64 ? e32[2 * i] : e32[i];
}
// async global->LDS: each lane copies 4B; lane i lands at ldst + i*4
static __device__ __forceinline__ void dma4(const void* g, void* l) {
    __builtin_amdgcn_global_load_lds(
        (const __attribute__((address_space(1))) void*)g,
        (__attribute__((address_space(3))) void*)l, 4, 0, 0);
}

// ---------------- dtype detection ----------------
__global__ void k_detect(const void* pos, const void* ei, int* flags) {
    __shared__ float smax[256];
    __shared__ int anynz;
    int t = threadIdx.x;
    if (t == 0) anynz = 0;
    const __hip_bfloat16* pb = (const __hip_bfloat16*)pos;
    float m = 0.f;
    for (int i = t; i < 2048; i += 256) {
        float v = fabsf(b2f(pb[i]));
        if (v != v) v = 1e30f;
        m = fmaxf(m, v);
    }
    smax[t] = m;
    __syncthreads();
    for (int s = 128; s > 0; s >>= 1) {
        if (t < s) smax[t] = fmaxf(smax[t], smax[t + s]);
        __syncthreads();
    }
    const int* e32 = (const int*)ei;
    if (t < 128 && e32[2 * t + 1] != 0) anynz = 1;
    __syncthreads();
    if (t == 0) {
        flags[0] = (smax[0] > 1e6f) ? 1 : 0;
        flags[1] = anynz ? 0 : 1;
    }
}

// ---------------- input assembly: x0 bf16 [N,8] (pads 0) ----------------
__global__ void k_build_x0(const void* __restrict__ pos, const void* __restrict__ nrm,
                           unsigned short* __restrict__ x0b, const int* __restrict__ flags) {
    int f32 = flags[0];
    int i = blockIdx.x * blockDim.x + threadIdx.x;
    if (i >= NN) return;
#pragma unroll
    for (int j = 0; j < 3; j++) {
        x0b[i * 8 + j]     = f32 ? f2bu(((const float*)pos)[i * 3 + j])
                                 : ((const unsigned short*)pos)[i * 3 + j];
        x0b[i * 8 + 3 + j] = f32 ? f2bu(((const float*)nrm)[i * 3 + j])
                                 : ((const unsigned short*)nrm)[i * 3 + j];
    }
    x0b[i * 8 + 6] = 0;
    x0b[i * 8 + 7] = 0;
}

// ---------------- CSR build: two-level counting sort ----------------
__global__ void __launch_bounds__(256) k_sortA(const int* __restrict__ ei,
                                               int* __restrict__ cntT,
                                               const int* __restrict__ flags) {
    __shared__ int hist[NBK];
    int i64 = flags[1];
    int t = threadIdx.x, w = blockIdx.x;
    for (int b = t; b < NBK; b += 256) hist[b] = 0;
    __syncthreads();
    int start = w * EPW, end = start + EPW;
    for (int e = start + t; e < end; e += 256) {
        int d = ldi(ei, NE + e, i64);
        atomicAdd(&hist[d >> 8], 1);
    }
    __syncthreads();
    for (int b = t; b < NBK; b += 256) cntT[b * SWG + w] = hist[b];
}

// -------- 3-phase exclusive scan over cntT[NBK*SWG] --------
__global__ void __launch_bounds__(256) k_scan_local(const int* __restrict__ a, int n,
                                                    int* __restrict__ o,
                                                    int* __restrict__ bsums) {
    __shared__ int ws[4];
    int b = blockIdx.x, t = threadIdx.x, lane = t & 63, wid = t >> 6;
    int idx = b * 256 + t;
    int v = (idx < n) ? a[idx] : 0;
    int incl = v;
#pragma unroll
    for (int off = 1; off < 64; off <<= 1) {
        int nb = __shfl_up(incl, off, 64);
        if (lane >= off) incl += nb;
    }
    if (lane == 63) ws[wid] = incl;
    __syncthreads();
    int wpre = 0, tot = 0;
#pragma unroll
    for (int wi = 0; wi < 4; wi++) {
        int s = ws[wi];
        if (wi < wid) wpre += s;
        tot += s;
    }
    if (idx < n) o[idx] = wpre + incl - v;
    if (t == 0) bsums[b] = tot;
}

__global__ void __launch_bounds__(256) k_scan_sums(const int* __restrict__ bsums,
                                                   int* __restrict__ bpre,
                                                   int* __restrict__ o, int n, int nb) {
    __shared__ int ws[4];
    int t = threadIdx.x, lane = t & 63, wid = t >> 6;
    int v = (t < nb) ? bsums[t] : 0;
    int incl = v;
#pragma unroll
    for (int off = 1; off < 64; off <<= 1) {
        int nbv = __shfl_up(incl, off, 64);
        if (lane >= off) incl += nbv;
    }
    if (lane == 63) ws[wid] = incl;
    __syncthreads();
    int wpre = 0, tot = 0;
#pragma unroll
    for (int wi = 0; wi < 4; wi++) {
        int s = ws[wi];
        if (wi < wid) wpre += s;
        tot += s;
    }
    if (t < nb) bpre[t] = wpre + incl - v;
    if (t == 0) o[n] = tot;
}

__global__ void __launch_bounds__(256) k_scan_add(int* __restrict__ o, int n,
                                                  const int* __restrict__ bpre) {
    int idx = blockIdx.x * 256 + threadIdx.x;
    if (idx < n) o[idx] += bpre[blockIdx.x];
}

// stage B: scatter packed {dloc,src} into per-(bucket,wg) contiguous ranges
__global__ void __launch_bounds__(256) k_sortB(const int* __restrict__ ei,
                                               const int* __restrict__ base2,
                                               unsigned int* __restrict__ ebuck,
                                               const int* __restrict__ flags) {
    __shared__ int cur[NBK];
    int i64 = flags[1];
    int t = threadIdx.x, w = blockIdx.x;
    for (int b = t; b < NBK; b += 256) cur[b] = base2[b * SWG + w];
    __syncthreads();
    int start = w * EPW, end = start + EPW;
    for (int e = start + t; e < end; e += 256) {
        int s = ldi(ei, e, i64), d = ldi(ei, NE + e, i64);
        int slot = atomicAdd(&cur[d >> 8], 1);
        ebuck[slot] = (unsigned int)s | ((unsigned int)(d & 255) << 16);
    }
}

// stage C: LDS counting sort within one bucket; writes offs + fine scatter
__global__ void __launch_bounds__(256) k_sortC(const unsigned int* __restrict__ ebuck,
                                               const int* __restrict__ base2,
                                               int* __restrict__ offs,
                                               int* __restrict__ ssrc) {
    __shared__ int cnt[256];
    __shared__ int ws[4];
    int t = threadIdx.x, b = blockIdx.x;
    int lane = t & 63, wid = t >> 6;
    cnt[t] = 0;
    __syncthreads();
    int bs = base2[b * SWG], be = base2[(b + 1) * SWG];
    for (int e = bs + t; e < be; e += 256)
        atomicAdd(&cnt[(ebuck[e] >> 16) & 255], 1);
    __syncthreads();
    int v = cnt[t];
    int incl = v;
#pragma unroll
    for (int off = 1; off < 64; off <<= 1) {
        int nb = __shfl_up(incl, off, 64);
        if (lane >= off) incl += nb;
    }
    if (lane == 63) ws[wid] = incl;
    __syncthreads();
    int wpre = 0;
#pragma unroll
    for (int wi = 0; wi < 4; wi++)
        if (wi < wid) wpre += ws[wi];
    int excl = wpre + incl - v;
    int gn = b * 256 + t;
    if (gn <= NN) offs[gn] = bs + excl;
    __syncthreads();
    cnt[t] = bs + excl;                // becomes the scatter cursor
    __syncthreads();
    for (int e = bs + t; e < be; e += 256) {
        unsigned int rec = ebuck[e];
        int slot = atomicAdd(&cnt[(rec >> 16) & 255], 1);
        ssrc[slot] = (int)(rec & 0xffffu);
    }
}

// ---------------- p = x @ u  ->  p8 [N,8] fp32 (h<6 valid) ----------------
__global__ void __launch_bounds__(256) k_compute_p6(const unsigned short* __restrict__ x0b,
                                                    const void* __restrict__ u,
                                                    float* __restrict__ p8,
                                                    const int* __restrict__ flags) {
    int f32 = flags[0];
    int wave = (blockIdx.x * blockDim.x + threadIdx.x) >> 6;
    int lane = threadIdx.x & 63;
    if (wave >= NN) return;
    float acc[HH] = {0, 0, 0, 0, 0, 0};
    if (lane < 6) {
        float xv = u2f(x0b[(size_t)wave * 8 + lane]);
#pragma unroll
        for (int h = 0; h < HH; h++) acc[h] = xv * ldf(u, lane * HH + h, f32);
    }
#pragma unroll
    for (int off = 4; off > 0; off >>= 1) {
#pragma unroll
        for (int h = 0; h < HH; h++) acc[h] += __shfl_down(acc[h], off, 64);
    }
    if (lane == 0) {
#pragma unroll
        for (int h = 0; h < HH; h++) p8[(size_t)wave * 8 + h] = acc[h];
    }
}

__global__ void __launch_bounds__(256) k_compute_p128(const unsigned short* __restrict__ x,
                                                      const void* __restrict__ u,
                                                      float* __restrict__ p8,
                                                      const int* __restrict__ flags) {
    int f32 = flags[0];
    int wave = (blockIdx.x * blockDim.x + threadIdx.x) >> 6;
    int lane = threadIdx.x & 63;
    if (wave >= NN) return;
    unsigned int w = *(const unsigned int*)(x + (size_t)wave * 128 + 2 * lane);
    float x0 = lo2f(w);
    float x1 = hi2f(w);
    float acc[HH];
#pragma unroll
    for (int h = 0; h < HH; h++)
        acc[h] = x0 * ldf(u, (2 * lane) * HH + h, f32) + x1 * ldf(u, (2 * lane + 1) * HH + h, f32);
#pragma unroll
    for (int off = 32; off > 0; off >>= 1) {
#pragma unroll
        for (int h = 0; h < HH; h++) acc[h] += __shfl_down(acc[h], off, 64);
    }
    if (lane == 0) {
#pragma unroll
        for (int h = 0; h < HH; h++) p8[(size_t)wave * 8 + h] = acc[h];
    }
}

// ---------------- fused softmax + aggregation, CIN=128 ----------
// Phase A: lane=edge, fp32 q[6]+rowElem -> 32B LDS entry. Phase B: broadcast
// ds_read_b128+b64 per edge (no unpack), rowElem via readlane (scalar),
// coalesced dword gather 8 deep, 12 scalar v_fma.
__global__ void __launch_bounds__(256) k_agg128(const unsigned short* __restrict__ xb,
                                                const float* __restrict__ p8,
                                                const void* __restrict__ cvec,
                                                const int* __restrict__ ssrc,
                                                const int* __restrict__ offs,
                                                unsigned short* __restrict__ agg,
                                                const int* __restrict__ flags) {
    __shared__ float qs[4][64][8];   // 8 KB: q0..q5, rowElem bits, pad
    int f32 = flags[0];
    int wid = threadIdx.x >> 6, lane = threadIdx.x & 63;
    int node = (blockIdx.x * blockDim.x + threadIdx.x) >> 6;
    if (node >= NN) return;
    int s0 = offs[node], s1 = offs[node + 1];
    int deg = s1 - s0;
    float scale = 1.0f / (float)(deg > 0 ? deg : 1);
    const float* pn = p8 + (size_t)node * 8;
    float pd[HH];
#pragma unroll
    for (int h = 0; h < HH; h++) pd[h] = pn[h] - ldf(cvec, h, f32);

    float a0[HH] = {}, a1[HH] = {};
    for (int base = s0; base < s1; base += 64) {
        int cnt = (s1 - base < 64) ? (s1 - base) : 64;
        // ---- phase A: lane = edge; fp32 q -> LDS; rowElem stays in reg ----
        unsigned int rowElem = 0;
        {
            int e = base + lane;
            float q0 = 0, q1 = 0, q2 = 0, q3 = 0, q4 = 0, q5 = 0;
            if (e < s1) {
                int j = ssrc[e];
                const float* pj = p8 + (size_t)j * 8;
                float4 pa = *(const float4*)pj;
                float2 pb = *(const float2*)(pj + 4);
                float t0 = pa.x - pd[0], t1 = pa.y - pd[1], t2 = pa.z - pd[2];
                float t3 = pa.w - pd[3], t4 = pb.x - pd[4], t5 = pb.y - pd[5];
                float mx = fmaxf(fmaxf(fmaxf(t0, t1), fmaxf(t2, t3)), fmaxf(t4, t5));
                q0 = __expf(t0 - mx); q1 = __expf(t1 - mx); q2 = __expf(t2 - mx);
                q3 = __expf(t3 - mx); q4 = __expf(t4 - mx); q5 = __expf(t5 - mx);
                float inv = 1.0f / (q0 + q1 + q2 + q3 + q4 + q5);
                q0 *= inv; q1 *= inv; q2 *= inv; q3 *= inv; q4 *= inv; q5 *= inv;
                rowElem = (unsigned int)j * 128u;
            }
            float4 qa = {q0, q1, q2, q3};
            float2 qb = {q4, q5};
            *(float4*)&qs[wid][lane][0] = qa;
            *(float2*)&qs[wid][lane][4] = qb;
        }
        // ---- phase B: broadcast LDS q + coalesced gather, 8 deep ----
        int cnt8 = (cnt + 7) & ~7;
        for (int s = 0; s < cnt8; s += 8) {
            unsigned int xw[8];
#pragma unroll
            for (int u = 0; u < 8; u++) {
                unsigned int ro =
                    (unsigned int)__builtin_amdgcn_readlane((int)rowElem, s + u);
                xw[u] = *(const unsigned int*)(xb + (size_t)ro + 2 * lane);
            }
#pragma unroll
            for (int u = 0; u < 8; u++) {
                float4 qa = *(const float4*)&qs[wid][s + u][0];   // broadcast
                float2 qb = *(const float2*)&qs[wid][s + u][4];
                float x0v = lo2f(xw[u]);
                float x1v = hi2f(xw[u]);
                a0[0] = fmaf(qa.x, x0v, a0[0]);
                a1[0] = fmaf(qa.x, x1v, a1[0]);
                a0[1] = fmaf(qa.y, x0v, a0[1]);
                a1[1] = fmaf(qa.y, x1v, a1[1]);
                a0[2] = fmaf(qa.z, x0v, a0[2]);
                a1[2] = fmaf(qa.z, x1v, a1[2]);
                a0[3] = fmaf(qa.w, x0v, a0[3]);
                a1[3] = fmaf(qa.w, x1v, a1[3]);
                a0[4] = fmaf(qb.x, x0v, a0[4]);
                a1[4] = fmaf(qb.x, x1v, a1[4]);
                a0[5] = fmaf(qb.y, x0v, a0[5]);
                a1[5] = fmaf(qb.y, x1v, a1[5]);
            }
        }
    }
    unsigned short* ar = agg + (size_t)node * 768;
#pragma unroll
    for (int h = 0; h < HH; h++) {
        *(unsigned int*)(ar + h * 128 + 2 * lane) = pk2(a0[h] * scale, a1[h] * scale);
    }
}

// ---------------- fused softmax + aggregation, CIN=6 (DMA staged) ---------
__global__ void __launch_bounds__(256) k_agg6(const unsigned short* __restrict__ xb,
                                              const float* __restrict__ p8,
                                              const void* __restrict__ cvec,
                                              const int* __restrict__ ssrc,
                                              const int* __restrict__ offs,
                                              float* __restrict__ agg,
                                              const int* __restrict__ flags) {
    __shared__ unsigned short stage6[4][64 * 8];     // 4 KB: 64 rows x 16 B
    __shared__ float qsf[4][64][8];                  // 8 KB: q[6] + rowbyte bits
    int f32 = flags[0];
    int wid = threadIdx.x >> 6, lane = threadIdx.x & 63;
    int node = (blockIdx.x * blockDim.x + threadIdx.x) >> 6;
    if (node >= NN) return;
    int s0 = offs[node], s1 = offs[node + 1];
    int deg = s1 - s0;
    float scale = 1.0f / (float)(deg > 0 ? deg : 1);
    const float* pn = p8 + (size_t)node * 8;
    float pd[HH];
#pragma unroll
    for (int h = 0; h < HH; h++) pd[h] = pn[h] - ldf(cvec, h, f32);

    float acc6 = 0.f;
    int hh6 = lane / 6, kk6 = lane - hh6 * 6;
    const char* xbase = (const char*)xb;
    for (int base = s0; base < s1; base += 64) {
        int cnt = (s1 - base < 64) ? (s1 - base) : 64;
        {
            int e = base + lane;
            float q0 = 0, q1 = 0, q2 = 0, q3 = 0, q4 = 0, q5 = 0;
            unsigned int rowByte = 0;
            if (e < s1) {
                int j = ssrc[e];
                const float* pj = p8 + (size_t)j * 8;
                float4 pa = *(const float4*)pj;
                float2 pb = *(const float2*)(pj + 4);
                float t0 = pa.x - pd[0], t1 = pa.y - pd[1], t2 = pa.z - pd[2];
                float t3 = pa.w - pd[3], t4 = pb.x - pd[4], t5 = pb.y - pd[5];
                float mx = fmaxf(fmaxf(fmaxf(t0, t1), fmaxf(t2, t3)), fmaxf(t4, t5));
                q0 = __expf(t0 - mx); q1 = __expf(t1 - mx); q2 = __expf(t2 - mx);
                q3 = __expf(t3 - mx); q4 = __expf(t4 - mx); q5 = __expf(t5 - mx);
                float inv = 1.0f / (q0 + q1 + q2 + q3 + q4 + q5);
                q0 *= inv; q1 *= inv; q2 *= inv; q3 *= inv; q4 *= inv; q5 *= inv;
                rowByte = (unsigned int)j * 16u;
            }
            float4 qa = {q0, q1, q2, q3};
            float4 qb = {q4, q5, __uint_as_float(rowByte), 0.f};
            *(float4*)&qsf[wid][lane][0] = qa;
            *(float4*)&qsf[wid][lane][4] = qb;
        }
        __builtin_amdgcn_sched_barrier(0);
#pragma unroll
        for (int t = 0; t < 4; t++) {
            int r = t * 16 + (lane >> 2);
            unsigned int rb = __float_as_uint(qsf[wid][r][6]);
            dma4(xbase + rb + (lane & 3) * 4, &stage6[wid][t * 128]);
        }
        __builtin_amdgcn_s_waitcnt(0x0f70);          // vmcnt(0) only
        __builtin_amdgcn_sched_barrier(0);
        if (lane < 36) {
            for (int s = 0; s < cnt; s++) {
                float qh = qsf[wid][s][hh6];
                float xv = u2f(stage6[wid][s * 8 + kk6]);
                acc6 = fmaf(qh, xv, acc6);
            }
        }
        __builtin_amdgcn_sched_barrier(0);
    }
    if (lane < 36) agg[(size_t)node * 36 + lane] = acc6 * scale;
}

// ---------------- fused weight repacks ----------------
__global__ void k_repack_all(const void* __restrict__ W1, const void* __restrict__ W2,
                             const void* __restrict__ W3, const void* __restrict__ W4,
                             const void* __restrict__ U4,
                             float* __restrict__ wstk1, unsigned short* __restrict__ wt2,
                             unsigned short* __restrict__ wt3, unsigned short* __restrict__ wt4,
                             unsigned short* __restrict__ u4,
                             const int* __restrict__ flags) {
    int f32 = flags[0];
    int idx = blockIdx.x * blockDim.x + threadIdx.x;
    if (idx < 4608) {
        int f = idx & 127, m = idx >> 7;
        int h = m / 6, k = m - h * 6;
        wstk1[idx] = ldf(W1, k * 768 + h * 128 + f, f32);
        return;
    }
    idx -= 4608;
    if (idx < 98304) {
        int f = idx / 768, m = idx % 768;
        int h = m >> 7, kk = m & 127;
        wt2[idx] = f2bu(ldf(W2, kk * 768 + h * 128 + f, f32));
        return;
    }
    idx -= 98304;
    if (idx < 98304) {
        int f = idx / 768, m = idx % 768;
        int h = m >> 7, kk = m & 127;
        wt3[idx] = f2bu(ldf(W3, kk * 768 + h * 128 + f, f32));
        return;
    }
    idx -= 98304;
    if (idx < 4096) {
        int n = idx >> 7, k = idx & 127;
        wt4[idx] = (n < 18) ? f2bu(ldf(W4, k * 18 + n, f32)) : (unsigned short)0;
        return;
    }
    idx -= 4096;
    if (idx < 2048) {
        int n = idx >> 7, k = idx & 127;
        u4[idx] = (n < 6) ? f2bu(ldf(U4, k * 6 + n, f32)) : (unsigned short)0;
    }
}

// ---------------- layer-1 GEMM (fp32, K=36), writes bf16 x ----------------
__global__ void __launch_bounds__(256) k_gemm_f32(const float* __restrict__ A,
                                                  const float* __restrict__ B,
                                                  const void* __restrict__ bias,
                                                  unsigned short* __restrict__ C,
                                                  int M, int K, int relu,
                                                  const int* __restrict__ flags) {
    int f32 = flags[0];
    __shared__ float As[16][68];
    __shared__ float Bs[16][128];
    int tid = threadIdx.x;
    int tx = tid & 15;
    int ty = tid >> 4;
    int bm = blockIdx.x * 64;
    int arow = tid >> 2, ak = (tid & 3) * 4;
    int brow = tid >> 4, bcol = (tid & 15) * 8;
    float acc[4][8] = {};
    for (int k0 = 0; k0 < K; k0 += 16) {
        float4 av = {0, 0, 0, 0};
        int gr = bm + arow;
        if (gr < M && (k0 + ak) < K) av = *(const float4*)(A + (size_t)gr * K + k0 + ak);
        As[ak + 0][arow] = av.x;
        As[ak + 1][arow] = av.y;
        As[ak + 2][arow] = av.z;
        As[ak + 3][arow] = av.w;
        float4 bv0 = {0, 0, 0, 0}, bv1 = {0, 0, 0, 0};
        if ((k0 + brow) < K) {
            const float* bp = B + (size_t)(k0 + brow) * 128 + bcol;
            bv0 = *(const float4*)bp;
            bv1 = *(const float4*)(bp + 4);
        }
        *(float4*)&Bs[brow][bcol]     = bv0;
        *(float4*)&Bs[brow][bcol + 4] = bv1;
        __syncthreads();
#pragma unroll
        for (int kk = 0; kk < 16; kk++) {
            float a_[4], b_[8];
#pragma unroll
            for (int j = 0; j < 4; j++) a_[j] = As[kk][ty * 4 + j];
#pragma unroll
            for (int j = 0; j < 8; j++) b_[j] = Bs[kk][tx * 8 + j];
#pragma unroll
            for (int i = 0; i < 4; i++)
#pragma unroll
                for (int j = 0; j < 8; j++) acc[i][j] = fmaf(a_[i], b_[j], acc[i][j]);
        }
        __syncthreads();
    }
#pragma unroll
    for (int i = 0; i < 4; i++) {
        int row = bm + ty * 4 + i;
        if (row >= M) continue;
#pragma unroll
        for (int j = 0; j < 8; j++) {
            int col = tx * 8 + j;
            float v = acc[i][j] + ldf(bias, col, f32);
            if (relu) v = fmaxf(v, 0.f);
            C[(size_t)row * 128 + col] = f2bu(v);
        }
    }
}

// ---------------- MFMA GEMM: C[M,128] = A[M,768]bf16 @ Wt^T + bias, ReLU ----
__global__ void __launch_bounds__(256) k_gemm_mfma(const unsigned short* __restrict__ A,
                                                   const unsigned short* __restrict__ Bt,
                                                   const void* __restrict__ bias,
                                                   unsigned short* __restrict__ C,
                                                   int M, int relu,
                                                   const int* __restrict__ flags) {
    constexpr int K = 768, BK = 64;
    __shared__ unsigned short As[64][72];
    __shared__ unsigned short Bs[128][72];
    int f32 = flags[0];
    int tid = threadIdx.x;
    int lane = tid & 63, wid = tid >> 6;
    int wm = wid & 1, wn = wid >> 1;
    int bm = blockIdx.x * 64;
    int l15 = lane & 15, lq = lane >> 4;
    f32x4 acc[2][4] = {};

    for (int k0 = 0; k0 < K; k0 += BK) {
#pragma unroll
        for (int cc = 0; cc < 2; cc++) {
            int c = tid + cc * 256;
            int r = c >> 3, kc = (c & 7) * 8;
            bf16x8 av = {};
            int gr = bm + r;
            if (gr < M) av = *(const bf16x8*)(A + (size_t)gr * K + k0 + kc);
            *(bf16x8*)&As[r][kc] = av;
        }
#pragma unroll
        for (int cc = 0; cc < 4; cc++) {
            int c = tid + cc * 256;
            int n = c >> 3, kc = (c & 7) * 8;
            *(bf16x8*)&Bs[n][kc] = *(const bf16x8*)(Bt + (size_t)n * K + k0 + kc);
        }
        __syncthreads();
#pragma unroll
        for (int ks = 0; ks < BK; ks += 32) {
            int koff = ks + lq * 8;
            bf16x8 af[2], bfr[4];
#pragma unroll
            for (int tm = 0; tm < 2; tm++)
                af[tm] = *(const bf16x8*)&As[wm * 32 + tm * 16 + l15][koff];
#pragma unroll
            for (int tn = 0; tn < 4; tn++)
                bfr[tn] = *(const bf16x8*)&Bs[wn * 64 + tn * 16 + l15][koff];
#pragma unroll
            for (int tm = 0; tm < 2; tm++)
#pragma unroll
                for (int tn = 0; tn < 4; tn++)
                    acc[tm][tn] = __builtin_amdgcn_mfma_f32_16x16x32_bf16(
                        af[tm], bfr[tn], acc[tm][tn], 0, 0, 0);
        }
        __syncthreads();
    }
#pragma unroll
    for (int tm = 0; tm < 2; tm++) {
#pragma unroll
        for (int tn = 0; tn < 4; tn++) {
            int col = wn * 64 + tn * 16 + l15;
            float bv = ldf(bias, col, f32);
#pragma unroll
            for (int r = 0; r < 4; r++) {
                int row = bm + wm * 32 + tm * 16 + lq * 4 + r;
                if (row < M) {
                    float v = acc[tm][tn][r] + bv;
                    if (relu) v = fmaxf(v, 0.f);
                    C[(size_t)row * 128 + col] = f2bu(v);
                }
            }
        }
    }
}

// ---------------- layer-4: y4 = x@W4 AND p = x@u in one MFMA kernel -------
__global__ void __launch_bounds__(256) k_y4p(const unsigned short* __restrict__ xb,
                                             const unsigned short* __restrict__ wt4,
                                             const unsigned short* __restrict__ u4,
                                             float* __restrict__ y4,
                                             float* __restrict__ p8) {
    int tid = threadIdx.x;
    int lane = tid & 63, wid = tid >> 6;
    int l15 = lane & 15, lq = lane >> 4;
    int bm = blockIdx.x * 64 + wid * 16;
    f32x4 acc[2] = {};
    f32x4 accp = {};
#pragma unroll
    for (int ks = 0; ks < 128; ks += 32) {
        int koff = ks + lq * 8;
        bf16x8 af = {};
        int row = bm + l15;
        if (row < NN) af = *(const bf16x8*)(xb + (size_t)row * 128 + koff);
        bf16x8 b0 = *(const bf16x8*)(wt4 + (0 * 16 + l15) * 128 + koff);
        bf16x8 b1 = *(const bf16x8*)(wt4 + (1 * 16 + l15) * 128 + koff);
        bf16x8 bu = *(const bf16x8*)(u4 + l15 * 128 + koff);
        acc[0] = __builtin_amdgcn_mfma_f32_16x16x32_bf16(af, b0, acc[0], 0, 0, 0);
        acc[1] = __builtin_amdgcn_mfma_f32_16x16x32_bf16(af, b1, acc[1], 0, 0, 0);
        accp = __builtin_amdgcn_mfma_f32_16x16x32_bf16(af, bu, accp, 0, 0, 0);
    }
#pragma unroll
    for (int t = 0; t < 2; t++) {
#pragma unroll
        for (int r = 0; r < 4; r++) {
            int row = bm + lq * 4 + r;
            int col = t * 16 + l15;
            if (row < NN && col < 18) y4[(size_t)row * 20 + col] = acc[t][r];
        }
    }
#pragma unroll
    for (int r = 0; r < 4; r++) {
        int row = bm + lq * 4 + r;
        if (row < NN && l15 < 6) p8[(size_t)row * 8 + l15] = accp[r];
    }
}

// ---------------- final layer: lane-per-edge over y4 ----------------------
__global__ void __launch_bounds__(256) k_final_fast(const float* __restrict__ y4,
                                                    const float* __restrict__ p8,
                                                    const void* __restrict__ cvec,
                                                    const int* __restrict__ ssrc,
                                                    const int* __restrict__ offs,
                                                    const void* __restrict__ bias,
                                                    void* __restrict__ out,
                                                    const int* __restrict__ flags) {
    int f32 = flags[0];
    int lane = threadIdx.x & 63;
    int node = (blockIdx.x * blockDim.x + threadIdx.x) >> 6;
    if (node >= NN) return;
    int s0 = offs[node], s1 = offs[node + 1];
    int deg = s1 - s0;
    float scale = 1.0f / (float)(deg > 0 ? deg : 1);
    const float* pn = p8 + (size_t)node * 8;
    float pd[HH];
#pragma unroll
    for (int h = 0; h < HH; h++) pd[h] = pn[h] - ldf(cvec, h, f32);

    float f0 = 0, f1 = 0, f2 = 0;
    for (int base = s0; base < s1; base += 64) {
        int e = base + lane;
        if (e < s1) {
            int j = ssrc[e];
            const float* pj = p8 + (size_t)j * 8;
            float4 pa = *(const float4*)pj;
            float2 pb = *(const float2*)(pj + 4);
            float t0 = pa.x - pd[0], t1 = pa.y - pd[1], t2 = pa.z - pd[2];
            float t3 = pa.w - pd[3], t4 = pb.x - pd[4], t5 = pb.y - pd[5];
            float mx = fmaxf(fmaxf(fmaxf(t0, t1), fmaxf(t2, t3)), fmaxf(t4, t5));
            float q0 = __expf(t0 - mx), q1 = __expf(t1 - mx), q2 = __expf(t2 - mx);
            float q3 = __expf(t3 - mx), q4 = __expf(t4 - mx), q5 = __expf(t5 - mx);
            float inv = 1.0f / (q0 + q1 + q2 + q3 + q4 + q5);
            float qa[6] = {q0 * inv, q1 * inv, q2 * inv, q3 * inv, q4 * inv, q5 * inv};
            const float* yr = y4 + (size_t)j * 20;
            float yv[20];
            *(float4*)&yv[0]  = *(const float4*)(yr + 0);
            *(float4*)&yv[4]  = *(const float4*)(yr + 4);
            *(float4*)&yv[8]  = *(const float4*)(yr + 8);
            *(float4*)&yv[12] = *(const float4*)(yr + 12);
            *(float4*)&yv[16] = *(const float4*)(yr + 16);
#pragma unroll
            for (int h = 0; h < HH; h++) {
                f0 = fmaf(qa[h], yv[3 * h + 0], f0);
                f1 = fmaf(qa[h], yv[3 * h + 1], f1);
                f2 = fmaf(qa[h], yv[3 * h + 2], f2);
            }
        }
    }
#pragma unroll
    for (int off = 32; off > 0; off >>= 1) {
        f0 += __shfl_down(f0, off, 64);
        f1 += __shfl_down(f1, off, 64);
        f2 += __shfl_down(f2, off, 64);
    }
    if (lane == 0) {
        float r0 = f0 * scale + ldf(bias, 0, f32);
        float r1 = f1 * scale + ldf(bias, 1, f32);
        float r2 = f2 * scale + ldf(bias, 2, f32);
        if (f32) {
            float* o = (float*)out;
            o[(size_t)node * 3 + 0] = r0;
            o[(size_t)node * 3 + 1] = r1;
            o[(size_t)node * 3 + 2] = r2;
        } else {
            __hip_bfloat16* o = (__hip_bfloat16*)out;
            o[(size_t)node * 3 + 0] = __float2bfloat16(r0);
            o[(size_t)node * 3 + 1] = __float2bfloat16(r1);
            o[(size_t)node * 3 + 2] = __float2bfloat16(r2);
        }
    }
}

extern "C" void kernel_launch(void* const* d_in, const int* in_sizes, int n_in,
                              void* d_out, int out_size, void* d_ws, size_t ws_size,
                              hipStream_t stream) {
    (void)in_sizes; (void)n_in; (void)out_size; (void)ws_size;
    const void* pos = d_in[0];
    const void* nrm = d_in[1];
    const int* ei = (const int*)d_in[2];
    const void* W[4] = {d_in[3], d_in[7], d_in[11], d_in[15]};
    const void* U[4] = {d_in[4], d_in[8], d_in[12], d_in[16]};
    const void* Cc[4] = {d_in[5], d_in[9], d_in[13], d_in[17]};
    const void* Bb[4] = {d_in[6], d_in[10], d_in[14], d_in[18]};

    char* wp = (char*)d_ws;
    auto alloc = [&](size_t b) { void* r = (void*)wp; wp += (b + 255) & ~(size_t)255; return r; };
    unsigned short* xA  = (unsigned short*)alloc((size_t)NN * 128 * 2);
    unsigned short* xB  = (unsigned short*)alloc((size_t)NN * 128 * 2);
    unsigned short* x0b = (unsigned short*)alloc((size_t)NN * 8 * 2);
    float* p8     = (float*)alloc((size_t)NN * 8 * 4);
    float* y4     = (float*)alloc((size_t)NN * 20 * 4);
    int*   offs   = (int*)alloc((size_t)(NN + 1) * 4);
    int*   cntT   = (int*)alloc((size_t)NBK * SWG * 4);
    int*   base2  = (int*)alloc((size_t)(NBK * SWG + 1) * 4);
    int*   bsums  = (int*)alloc((size_t)256 * 4);
    int*   bpre   = (int*)alloc((size_t)256 * 4);
    int*   flags  = (int*)alloc(256);
    int*   ssrc   = (int*)alloc((size_t)NE * 4);
    unsigned int* ebuck = (unsigned int*)alloc((size_t)NE * 4);
    void*  aggv   = alloc((size_t)NN * 768 * 2);
    float* wstk1  = (float*)alloc((size_t)36 * 128 * 4);
    unsigned short* wt2 = (unsigned short*)alloc((size_t)128 * 768 * 2);
    unsigned short* wt3 = (unsigned short*)alloc((size_t)128 * 768 * 2);
    unsigned short* wt4 = (unsigned short*)alloc((size_t)32 * 128 * 2);
    unsigned short* u4  = (unsigned short*)alloc((size_t)16 * 128 * 2);
    unsigned short* agg_h = (unsigned short*)aggv;
    float* agg_f = (float*)aggv;

    const int NB = (NN + 255) / 256;
    const int NWB = (NN * 64 + 255) / 256;      // 256-thread wave-per-node grids
    const int GB = (NN + 63) / 64;
    const int NSC = NBK * SWG;                   // 50176

    k_detect<<<1, 256, 0, stream>>>(pos, ei, flags);
    k_sortA<<<SWG, 256, 0, stream>>>(ei, cntT, flags);
    k_scan_local<<<NBK, 256, 0, stream>>>(cntT, NSC, base2, bsums);
    k_scan_sums<<<1, 256, 0, stream>>>(bsums, bpre, base2, NSC, NBK);
    k_scan_add<<<NBK, 256, 0, stream>>>(base2, NSC, bpre);
    k_sortB<<<SWG, 256, 0, stream>>>(ei, base2, ebuck, flags);
    k_sortC<<<NBK, 256, 0, stream>>>(ebuck, base2, offs, ssrc);
    k_build_x0<<<NB, 256, 0, stream>>>(pos, nrm, x0b, flags);
    k_repack_all<<<(207360 + 255) / 256, 256, 0, stream>>>(W[0], W[1], W[2], W[3], U[3],
                                                           wstk1, wt2, wt3, wt4, u4, flags);

    // ---- layer 1: 6 -> 128, relu ----
    k_compute_p6<<<NWB, 256, 0, stream>>>(x0b, U[0], p8, flags);
    k_agg6<<<NWB, 256, 0, stream>>>(x0b, p8, Cc[0], ssrc, offs, agg_f, flags);
    k_gemm_f32<<<GB, 256, 0, stream>>>(agg_f, wstk1, Bb[0], xA, NN, 36, 1, flags);

    // ---- layer 2: 128 -> 128, relu ----
    k_compute_p128<<<NWB, 256, 0, stream>>>(xA, U[1], p8, flags);
    k_agg128<<<NWB, 256, 0, stream>>>(xA, p8, Cc[1], ssrc, offs, agg_h, flags);
    k_gemm_mfma<<<GB, 256, 0, stream>>>(agg_h, wt2, Bb[1], xB, NN, 1, flags);

    // ---- layer 3: 128 -> 128, relu ----
    k_compute_p128<<<NWB, 256, 0, stream>>>(xB, U[2], p8, flags);
    k_agg128<<<NWB, 256, 0, stream>>>(xB, p8, Cc[2], ssrc, offs, agg_h, flags);
    k_gemm_mfma<<<GB, 256, 0, stream>>>(agg_h, wt3, Bb[2], xA, NN, 1, flags);

    // ---- layer 4: 128 -> 3 (transform-first; y4 + p fused) ----
    k_y4p<<<GB, 256, 0, stream>>>(xA, wt4, u4, y4, p8);
    k_final_fast<<<NWB, 256, 0, stream>>>(y4, p8, Cc[3], ssrc, offs, Bb[3], d_out, flags);
}